// Round 1
// 1588.724 us; speedup vs baseline: 1.0229x; 1.0229x over previous
//
#include <hip/hip_runtime.h>
#include <hip/hip_bf16.h>
#include <math.h>

// ============================================================================
// ImprovedTransformerBlock on MI355X.  R4: gemm_bt_kernel k-loop restructured
// to a 2-phase double-buffered pipeline (T3-minimum): STAGE(next tile) issued
// BEFORE ds_read+MFMA(current), ONE __syncthreads per tile (was 2 barriers +
// full load-latency exposure per BK=32 step).  LDS: split 64KB (2 blk/CU),
// non-split 32KB (5 blk/CU).  Everything else unchanged from R3.
// Precision plan: pre-gate path bf16x2-split MFMA (fp32-grade, protects top-2
// routing); post-gate (experts, FFN) plain bf16 MFMA.
// ============================================================================

typedef unsigned short UST;
typedef unsigned int uint32;
typedef float f32x4 __attribute__((ext_vector_type(4)));
using s16x8 = __attribute__((ext_vector_type(8))) short;   // 8 bf16 = 4 VGPRs

#define DEV __device__ __forceinline__
#define MFMA16 __builtin_amdgcn_mfma_f32_16x16x32_bf16

// async global->LDS, 16 bytes/lane; lds dst is wave-uniform base + lane*16
#define GLL(g, l) __builtin_amdgcn_global_load_lds( \
    (const __attribute__((address_space(1))) unsigned int*)(g), \
    (__attribute__((address_space(3))) unsigned int*)(l), 16, 0, 0)

DEV UST f2bf(float f) {                       // round-to-nearest-even fp32->bf16
    uint32 u = __float_as_uint(f);
    u += 0x7FFFu + ((u >> 16) & 1u);
    return (UST)(u >> 16);
}
DEV float bf2f(UST h) { return __uint_as_float(((uint32)h) << 16); }
DEV float gelu_f(float x) { return 0.5f * x * (1.0f + erff(x * 0.7071067811865475f)); }

// ---------------------------------------------------------------------------
// LayerNorm -> split bf16 (hi/lo), conv-padded row layout: row(t)=t+2+4*(t>>12)
// ---------------------------------------------------------------------------
__global__ void ln_split_kernel(const float* __restrict__ x,
                                const float* __restrict__ g, const float* __restrict__ b,
                                UST* __restrict__ oh, UST* __restrict__ ol)
{
    const int t = blockIdx.x;
    const int tid = threadIdx.x;
    const float4 v = ((const float4*)(x + (long)t * 1024))[tid];
    float s = v.x + v.y + v.z + v.w;
    float q = v.x * v.x + v.y * v.y + v.z * v.z + v.w * v.w;
    for (int o = 32; o > 0; o >>= 1) { s += __shfl_xor(s, o, 64); q += __shfl_xor(q, o, 64); }
    __shared__ float ss[4], sq[4];
    const int wave = tid >> 6, lane = tid & 63;
    if (lane == 0) { ss[wave] = s; sq[wave] = q; }
    __syncthreads();
    s = ss[0] + ss[1] + ss[2] + ss[3];
    q = sq[0] + sq[1] + sq[2] + sq[3];
    const float mean = s * (1.0f / 1024.0f);
    const float var = q * (1.0f / 1024.0f) - mean * mean;
    const float rstd = 1.0f / sqrtf(var + 1e-5f);
    const long row = (long)t + 2 + 4 * (t >> 12);
    UST* ph = oh + row * 1024 + tid * 4;
    UST* pl = ol + row * 1024 + tid * 4;
    const float4 gg = ((const float4*)g)[tid];
    const float4 bb = ((const float4*)b)[tid];
    float vv[4] = { v.x, v.y, v.z, v.w };
    float gv[4] = { gg.x, gg.y, gg.z, gg.w };
    float bv[4] = { bb.x, bb.y, bb.z, bb.w };
#pragma unroll
    for (int j = 0; j < 4; j++) {
        float f = (vv[j] - mean) * rstd * gv[j] + bv[j];
        UST hi = f2bf(f);
        ph[j] = hi;
        pl[j] = f2bf(f - bf2f(hi));
    }
}

// zero the conv-pad rows {b*4100 + 0,1,4098,4099} of LNh/LNl
__global__ void ln_pad_kernel(UST* __restrict__ oh, UST* __restrict__ ol)
{
    const int blk = blockIdx.x;          // 8 blocks
    const int b = blk >> 2, rsel = blk & 3;
    const long row = (long)b * 4100 + (rsel < 2 ? rsel : 4096 + rsel);
    const int tid = threadIdx.x;
    *(ushort4*)(oh + row * 1024 + tid * 4) = make_ushort4(0, 0, 0, 0);
    *(ushort4*)(ol + row * 1024 + tid * 4) = make_ushort4(0, 0, 0, 0);
}

// ---------------------------------------------------------------------------
// Coalesced transpose prep: dst[n*K+k] = src[k*N+n], bf16 hi (+lo).
// ---------------------------------------------------------------------------
__global__ void prep_t_kernel(const float* __restrict__ src, UST* __restrict__ dh,
                              UST* __restrict__ dl, int N, int K)
{
    __shared__ float tile[32][65];
    const int k0 = blockIdx.y * 32, n0 = blockIdx.x * 64;
    const int t = threadIdx.x;
    const int nn = t & 63, kk = t >> 6;
#pragma unroll
    for (int i = 0; i < 8; i++)
        tile[kk + i * 4][nn] = src[(long)(k0 + kk + i * 4) * N + n0 + nn];
    __syncthreads();
    const int kw = (t & 7) * 4;
#pragma unroll
    for (int pass = 0; pass < 2; pass++) {
        const int nw = (t >> 3) + pass * 32;
        UST hv[4], lv[4];
#pragma unroll
        for (int j = 0; j < 4; j++) {
            float v = tile[kw + j][nw];
            hv[j] = f2bf(v);
            lv[j] = f2bf(v - bf2f(hv[j]));
        }
        UST* bh = dh + (long)(n0 + nw) * K + k0 + kw;
        *(ushort4*)bh = make_ushort4(hv[0], hv[1], hv[2], hv[3]);
        if (dl) {
            UST* bl = dl + (long)(n0 + nw) * K + k0 + kw;
            *(ushort4*)bl = make_ushort4(lv[0], lv[1], lv[2], lv[3]);
        }
    }
}

// conv taps into concatenated B: dst[n*dstK + dstOff + k] = src[k*sr + n*sc]
__global__ void prep_w_kernel(const float* __restrict__ src, UST* __restrict__ dh,
                              UST* __restrict__ dl, int K, long sr, long sc,
                              int dstK, int dstOff, long total)
{
    long gid = (long)blockIdx.x * 256 + threadIdx.x;
    if (gid >= total) return;
    long n = gid / K, k = gid - n * K;
    float v = src[k * sr + n * sc];
    UST hi = f2bf(v);
    long di = n * dstK + dstOff + k;
    dh[di] = hi;
    if (dl) dl[di] = f2bf(v - bf2f(hi));
}

// ---------------------------------------------------------------------------
// GEMM: C[M,N] = A[M,K] * B^T[N,K]  (bf16, fp32 accum, MFMA 16x16x32)
// 128x128 tile, BK=32, 256 threads, global_load_lds(16B) staging.
// R4: 2-phase double-buffered pipeline — stage(t+1) issued before compute(t),
// one __syncthreads per tile.  K is always a multiple of 64 here, so the loop
// is 2x-unrolled with compile-time LDS buffer bases.
// SPLIT: A=Ah+Al, B=Bh+Bl -> AhBh + AhBl + AlBh (fp32-grade).
// A row stride KA; A k-offset = k0 + (k0>>10)*ASHIFT (conv seg trick: segment
// s reads +2048 elements = +2 rows -> tap s hits row t+2s).
// EPI 0: Cf = acc(+bias)(+resid) fp32. EPI 1: Cb = bf16(gelu(acc+bias)).
// EPI 2: scatter split bf16 into Sp = [Qh|Ql|Kh|Kl|Vth|Vtl] (attention prep).
// ---------------------------------------------------------------------------
template<int EPI, bool SPLIT, int ASHIFT>
__global__ __launch_bounds__(256)
void gemm_bt_kernel(const UST* __restrict__ Ah, const UST* __restrict__ Al,
                    const UST* __restrict__ Bh, const UST* __restrict__ Bl,
                    const float* __restrict__ bias, const float* __restrict__ resid,
                    float* __restrict__ Cf, UST* __restrict__ Cb, UST* __restrict__ Sp,
                    int M, int N, int K, int KA, int rb, int radd)
{
    constexpr int ABUF = (SPLIT ? 2 : 1) * 4096;   // USTs per k-tile buffer
    __shared__ UST sA[2 * ABUF];
    __shared__ UST sB[2 * ABUF];
    const int tid = threadIdx.x;
    const int lane = tid & 63;
    const int wv = __builtin_amdgcn_readfirstlane(tid >> 6);
    const int wr = wv >> 1, wc = wv & 1;
    const int lm = lane & 15, lq = lane >> 4;
    const long m0 = (long)blockIdx.y * 128, n0 = (long)blockIdx.x * 128;

    const int lr = lane >> 2, lc = (lane & 3) * 8;
    const int rA0 = wv * 32 + lr, rA1 = wv * 32 + 16 + lr;
    const long mtop = m0 >> 12;              // tiles never straddle 4096 rows
    const UST* gA0 = Ah + (m0 + rA0 + rb + (long)radd * mtop) * KA + lc;
    const UST* gA1 = Ah + (m0 + rA1 + rb + (long)radd * mtop) * KA + lc;
    const UST* gB0 = Bh + (n0 + rA0) * K + lc;
    const UST* gB1 = Bh + (n0 + rA1) * K + lc;
    const UST* gA0l = SPLIT ? (Al + (m0 + rA0 + rb + (long)radd * mtop) * KA + lc) : nullptr;
    const UST* gA1l = SPLIT ? (Al + (m0 + rA1 + rb + (long)radd * mtop) * KA + lc) : nullptr;
    const UST* gB0l = SPLIT ? (Bl + (n0 + rA0) * K + lc) : nullptr;
    const UST* gB1l = SPLIT ? (Bl + (n0 + rA1) * K + lc) : nullptr;

    f32x4 acc[4][4] = {};

    // stage k-tile kk into buffer with per-wave bases dA/dB (wave-uniform)
    auto stage = [&](int kk, UST* dA, UST* dB) {
        const long aoff = ASHIFT ? (long)kk + (long)(kk >> 10) * ASHIFT : (long)kk;
        GLL(gA0 + aoff, dA); GLL(gA1 + aoff, dA + 512);
        GLL(gB0 + kk, dB); GLL(gB1 + kk, dB + 512);
        if (SPLIT) {
            GLL(gA0l + aoff, dA + 4096); GLL(gA1l + aoff, dA + 512 + 4096);
            GLL(gB0l + kk, dB + 4096); GLL(gB1l + kk, dB + 512 + 4096);
        }
    };
    // consume one staged k-tile at LDS bases cA/cB
    auto compute = [&](const UST* cA, const UST* cB) {
        s16x8 ah[4], bh[4];
#pragma unroll
        for (int i = 0; i < 4; i++) {
            ah[i] = *(const s16x8*)&cA[(wr * 64 + i * 16 + lm) * 32 + lq * 8];
            bh[i] = *(const s16x8*)&cB[(wc * 64 + i * 16 + lm) * 32 + lq * 8];
        }
#pragma unroll
        for (int i = 0; i < 4; i++)
#pragma unroll
            for (int j = 0; j < 4; j++)
                acc[i][j] = MFMA16(ah[i], bh[j], acc[i][j], 0, 0, 0);
        if (SPLIT) {
            s16x8 al[4], bl[4];
#pragma unroll
            for (int i = 0; i < 4; i++) {
                al[i] = *(const s16x8*)&cA[4096 + (wr * 64 + i * 16 + lm) * 32 + lq * 8];
                bl[i] = *(const s16x8*)&cB[4096 + (wc * 64 + i * 16 + lm) * 32 + lq * 8];
            }
#pragma unroll
            for (int i = 0; i < 4; i++)
#pragma unroll
                for (int j = 0; j < 4; j++) {
                    acc[i][j] = MFMA16(ah[i], bl[j], acc[i][j], 0, 0, 0);
                    acc[i][j] = MFMA16(al[i], bh[j], acc[i][j], 0, 0, 0);
                }
        }
    };

    UST* wA0 = &sA[wv * 1024];
    UST* wB0 = &sB[wv * 1024];
    UST* wA1 = &sA[ABUF + wv * 1024];
    UST* wB1 = &sB[ABUF + wv * 1024];

    stage(0, wA0, wB0);
    __syncthreads();                          // drains prologue stage (vmcnt 0)
    for (int k0 = 0; k0 < K; k0 += 64) {
        stage(k0 + 32, wA1, wB1);             // k0+32 < K always (K % 64 == 0)
        compute(&sA[0], &sB[0]);
        __syncthreads();                      // stage(buf1) drained; buf0 reads done
        if (k0 + 64 < K) stage(k0 + 64, wA0, wB0);
        compute(&sA[ABUF], &sB[ABUF]);
        __syncthreads();                      // stage(buf0) drained; buf1 reads done
    }

    // C/D layout (m89/m91-verified): col = lane&15, row = (lane>>4)*4 + reg
    const long SZ = 8388608L;
    const int colbase = (int)n0 + wc * 64;          // wave-uniform
    const int part = colbase >> 10;                 // EPI2: 0=Q,1=K,2=V
    const int hh = (colbase & 1023) >> 6;
    UST* H = (EPI == 2) ? (Sp + (long)part * 2 * SZ) : nullptr;
    UST* Lo = (EPI == 2) ? (H + SZ) : nullptr;
#pragma unroll
    for (int i = 0; i < 4; i++) {
#pragma unroll
        for (int j = 0; j < 4; j++) {
#pragma unroll
            for (int r = 0; r < 4; r++) {
                const long grow = m0 + wr * 64 + i * 16 + lq * 4 + r;
                const long gcol = n0 + wc * 64 + j * 16 + lm;
                float v = acc[i][j][r];
                if (bias) v += bias[gcol];
                if (EPI == 0) {
                    const long idx = grow * N + gcol;
                    if (resid) v += resid[idx];
                    Cf[idx] = v;
                } else if (EPI == 1) {
                    Cb[grow * N + gcol] = f2bf(gelu_f(v));
                } else {
                    const int d = j * 16 + lm;      // col within head
                    long idx;
                    if (part < 2) {
                        idx = ((long)hh * 8192 + grow) * 64 + d;
                    } else {
                        const int bb = (int)(grow >> 12), ww = (int)((grow >> 8) & 15),
                                  tt = (int)(grow & 255);
                        idx = ((long)((bb * 16 + ww) * 16 + hh)) * 16384 + (long)d * 256 + tt;
                    }
                    UST hi = f2bf(v);
                    H[idx] = hi;
                    Lo[idx] = f2bf(v - bf2f(hi));
                }
            }
        }
    }
}

// ---------------------------------------------------------------------------
// MFMA windowed attention (split-bf16, fp32-grade). Block = (b,win,head),
// 4 waves; wave owns 64 q-rows, iterates 8 k-chunks of 32 keys.
// S = QhKh+QhKl+QlKh (fp32 acc) -> P = exp(S/8) fp32 (scores bounded, no max)
// -> P split hi/lo through per-wave LDS (stride 40, 16B-aligned frag reads)
// -> O += PhVh+PhVl+PlVh.  l accumulated via cross-lane xor-reduce.
// Q frags live in registers whole kernel; K/V frags read from global (L2).
// ---------------------------------------------------------------------------
__global__ __launch_bounds__(256, 2)
void attn_mfma_kernel(const UST* __restrict__ Sp, UST* __restrict__ oh, UST* __restrict__ ol)
{
    __shared__ UST sPh[4 * 64 * 40];
    __shared__ UST sPl[4 * 64 * 40];
    const long SZ = 8388608L;
    const UST* Qh = Sp;
    const UST* Ql = Sp + SZ;
    const UST* Kh = Sp + 2 * SZ;
    const UST* Kl = Sp + 3 * SZ;
    const UST* Vth = Sp + 4 * SZ;
    const UST* Vtl = Sp + 5 * SZ;
    const int blk = blockIdx.x;
    const int h = blk & 15, w = (blk >> 4) & 15, b = blk >> 8;
    const long tok0 = (long)b * 4096 + w * 256;
    const int tid = threadIdx.x;
    const int lane = tid & 63;
    const int wv = tid >> 6;
    const int lm = lane & 15, lq = lane >> 4;

    // Q fragments (A-operand: m=lane&15, k=(lane>>4)*8+j), resident all kernel
    const long qrow0 = (long)h * 8192 + tok0 + wv * 64;
    s16x8 qhf[4][2], qlf[4][2];
#pragma unroll
    for (int mt = 0; mt < 4; mt++)
#pragma unroll
        for (int ks = 0; ks < 2; ks++) {
            const long o = (qrow0 + mt * 16 + lm) * 64 + ks * 32 + lq * 8;
            qhf[mt][ks] = *(const s16x8*)(Qh + o);
            qlf[mt][ks] = *(const s16x8*)(Ql + o);
        }
    const long krow0 = (long)h * 8192 + tok0;
    const long vbase = (long)blk * 16384;

    f32x4 Oacc[4][4] = {};
    float lsum[4][4] = {};
    UST* myPh = &sPh[wv * 2560];
    UST* myPl = &sPl[wv * 2560];

    for (int c = 0; c < 8; c++) {
        const int kt = c * 32;
        // ---- S = Q K^T (64q x 32k), split 3-product ----
        f32x4 S[4][2] = {};
#pragma unroll
        for (int nt = 0; nt < 2; nt++)
#pragma unroll
            for (int ks = 0; ks < 2; ks++) {
                const long o = (krow0 + kt + nt * 16 + lm) * 64 + ks * 32 + lq * 8;
                s16x8 khf = *(const s16x8*)(Kh + o);
                s16x8 klf = *(const s16x8*)(Kl + o);
#pragma unroll
                for (int mt = 0; mt < 4; mt++) {
                    S[mt][nt] = MFMA16(qhf[mt][ks], khf, S[mt][nt], 0, 0, 0);
                    S[mt][nt] = MFMA16(qhf[mt][ks], klf, S[mt][nt], 0, 0, 0);
                    S[mt][nt] = MFMA16(qlf[mt][ks], khf, S[mt][nt], 0, 0, 0);
                }
            }
        // ---- P = exp(S/8); l partial; write P split to LDS ----
#pragma unroll
        for (int mt = 0; mt < 4; mt++)
#pragma unroll
            for (int r = 0; r < 4; r++) {
                float p0 = __expf(S[mt][0][r] * 0.125f);
                float p1 = __expf(S[mt][1][r] * 0.125f);
                float part = p0 + p1;
                part += __shfl_xor(part, 1, 64);
                part += __shfl_xor(part, 2, 64);
                part += __shfl_xor(part, 4, 64);
                part += __shfl_xor(part, 8, 64);
                lsum[mt][r] += part;
                const int q = mt * 16 + lq * 4 + r;
                UST h0 = f2bf(p0), h1 = f2bf(p1);
                myPh[q * 40 + lm] = h0;
                myPh[q * 40 + 16 + lm] = h1;
                myPl[q * 40 + lm] = f2bf(p0 - bf2f(h0));
                myPl[q * 40 + 16 + lm] = f2bf(p1 - bf2f(h1));
            }
        // ---- O += P V (P from LDS A-frags, V^T from global B-frags) ----
#pragma unroll
        for (int mt = 0; mt < 4; mt++) {
            s16x8 phf = *(const s16x8*)(myPh + (mt * 16 + lm) * 40 + lq * 8);
            s16x8 plf = *(const s16x8*)(myPl + (mt * 16 + lm) * 40 + lq * 8);
#pragma unroll
            for (int dt = 0; dt < 4; dt++) {
                const long o = vbase + (dt * 16 + lm) * 256 + kt + lq * 8;
                s16x8 vhf = *(const s16x8*)(Vth + o);
                s16x8 vlf = *(const s16x8*)(Vtl + o);
                Oacc[mt][dt] = MFMA16(phf, vhf, Oacc[mt][dt], 0, 0, 0);
                Oacc[mt][dt] = MFMA16(phf, vlf, Oacc[mt][dt], 0, 0, 0);
                Oacc[mt][dt] = MFMA16(plf, vhf, Oacc[mt][dt], 0, 0, 0);
            }
        }
    }
    // ---- normalize + write split bf16 ----
#pragma unroll
    for (int mt = 0; mt < 4; mt++)
#pragma unroll
        for (int r = 0; r < 4; r++) {
            const float inv = 1.0f / lsum[mt][r];
            const long tok = tok0 + wv * 64 + mt * 16 + lq * 4 + r;
            UST* po = oh + tok * 1024 + h * 64;
            UST* plo = ol + tok * 1024 + h * 64;
#pragma unroll
            for (int dt = 0; dt < 4; dt++) {
                float f = Oacc[mt][dt][r] * inv;
                UST hv = f2bf(f);
                po[dt * 16 + lm] = hv;
                plo[dt * 16 + lm] = f2bf(f - bf2f(hv));
            }
        }
}

// ---------------------------------------------------------------------------
// Gate: logits (hi+lo fp32-grade), softmax, entropy, top-2 -> combine weights.
// ---------------------------------------------------------------------------
__global__ void gate_kernel(const UST* __restrict__ lnh, const UST* __restrict__ lnl,
                            const float* __restrict__ gw, const float* __restrict__ gb,
                            float* __restrict__ combine, float* __restrict__ ent_acc)
{
    const int tid = threadIdx.x;
    const int t = blockIdx.x * 4 + (tid >> 6);
    const int lane = tid & 63;
    const long row = (long)t + 2 + 4 * (t >> 12);
    const UST* ph = lnh + row * 1024;
    const UST* pl = lnl + row * 1024;
    float acc[8] = { 0, 0, 0, 0, 0, 0, 0, 0 };
    for (int c = 0; c < 16; c++) {
        int d = c * 64 + lane;
        float xv = bf2f(ph[d]) + bf2f(pl[d]);
        const float* wr = gw + (long)d * 8;
#pragma unroll
        for (int e = 0; e < 8; e++) acc[e] += xv * wr[e];
    }
#pragma unroll
    for (int e = 0; e < 8; e++)
        for (int o = 32; o > 0; o >>= 1) acc[e] += __shfl_xor(acc[e], o, 64);
    if (lane == 0) {
        float lg[8], p[8];
        float mx = -1e30f;
        for (int e = 0; e < 8; e++) { lg[e] = acc[e] + gb[e]; mx = fmaxf(mx, lg[e]); }
        float sum = 0;
        for (int e = 0; e < 8; e++) { p[e] = expf(lg[e] - mx); sum += p[e]; }
        float inv = 1.0f / sum;
        float ent = 0;
        for (int e = 0; e < 8; e++) { p[e] *= inv; ent -= p[e] * logf(p[e] + 1e-10f); }
        int i1 = 0; float v1 = -1e30f;
        for (int e = 0; e < 8; e++) if (p[e] > v1) { v1 = p[e]; i1 = e; }
        int i2 = 0; float v2 = -1e30f;
        for (int e = 0; e < 8; e++) if (e != i1 && p[e] > v2) { v2 = p[e]; i2 = e; }
        float inv2 = 1.0f / (v1 + v2);
        float cw[8] = { 0, 0, 0, 0, 0, 0, 0, 0 };
        cw[i1] = v1 * inv2; cw[i2] = v2 * inv2;
        float* co = combine + (long)t * 8;
        for (int e = 0; e < 8; e++) co[e] = cw[e];
        atomicAdd(ent_acc, ent);
    }
}

// out[t,f] += sum_j combine[t, half*4+j] * y[t, j*1024+f]
__global__ void moe_combine_kernel(const UST* __restrict__ y, const float* __restrict__ combine,
                                   float* __restrict__ out, int halfsel)
{
    const long gid = (long)blockIdx.x * 256 + threadIdx.x;
    const int t = (int)(gid >> 10), f = (int)(gid & 1023);
    const float* cw = combine + (long)t * 8 + halfsel * 4;
    const UST* yp = y + (long)t * 4096 + f;
    float s = cw[0] * bf2f(yp[0]) + cw[1] * bf2f(yp[1024])
            + cw[2] * bf2f(yp[2048]) + cw[3] * bf2f(yp[3072]);
    out[gid] += s;
}

__global__ void f32_to_bf16_kernel(const float* __restrict__ in, UST* __restrict__ out)
{
    long gid = ((long)blockIdx.x * 256 + threadIdx.x) * 4;
    float4 v = *(const float4*)(in + gid);
    out[gid] = f2bf(v.x); out[gid + 1] = f2bf(v.y);
    out[gid + 2] = f2bf(v.z); out[gid + 3] = f2bf(v.w);
}

__global__ void ent_final_kernel(const float* __restrict__ acc, float* __restrict__ out)
{
    out[0] = 0.1f * acc[0] * (1.0f / 8192.0f);
}

// ===========================================================================
extern "C" void kernel_launch(void* const* d_in, const int* in_sizes, int n_in,
                              void* d_out_, int out_size, void* d_ws, size_t ws_size,
                              hipStream_t stream)
{
    const float* x      = (const float*)d_in[0];
    const float* ln1_g  = (const float*)d_in[1];
    const float* ln1_b  = (const float*)d_in[2];
    const float* qkv_w  = (const float*)d_in[3];
    const float* qkv_b  = (const float*)d_in[4];
    const float* ao_w   = (const float*)d_in[5];
    const float* ao_b   = (const float*)d_in[6];
    const float* ln2_g  = (const float*)d_in[7];
    const float* ln2_b  = (const float*)d_in[8];
    const float* conv_w = (const float*)d_in[9];
    const float* conv_b = (const float*)d_in[10];
    const float* ln3_g  = (const float*)d_in[11];
    const float* ln3_b  = (const float*)d_in[12];
    const float* gate_w = (const float*)d_in[13];
    const float* gate_b = (const float*)d_in[14];
    const float* exp_w  = (const float*)d_in[15];
    const float* exp_b  = (const float*)d_in[16];
    const float* ff_w1  = (const float*)d_in[17];
    const float* ff_b1  = (const float*)d_in[18];
    const float* ff_w2  = (const float*)d_in[19];
    const float* ff_b2  = (const float*)d_in[20];
    float* out = (float*)d_out_;

    char* ws = (char*)d_ws;
    size_t off = 0;
    auto alloc = [&](size_t bytes) -> char* {
        char* p = ws + off;
        off += (bytes + 255) & ~(size_t)255;
        return p;
    };
    UST* qkvWh = (UST*)alloc(3072 * 1024 * 2);
    UST* qkvWl = (UST*)alloc(3072 * 1024 * 2);
    UST* aoWh  = (UST*)alloc(1024 * 1024 * 2);
    UST* aoWl  = (UST*)alloc(1024 * 1024 * 2);
    UST* convCh = (UST*)alloc(1024L * 3072 * 2);   // [n=1024][k=3072] concat taps
    UST* convCl = (UST*)alloc(1024L * 3072 * 2);
    UST* expW  = (UST*)alloc(8192L * 1024 * 2);
    UST* ff1W  = (UST*)alloc(4096L * 1024 * 2);
    UST* ff2W  = (UST*)alloc(4096L * 1024 * 2);
    const size_t LN_BYTES = 8200L * 1024 * 2;
    UST* LNh = (UST*)alloc(LN_BYTES);
    UST* LNl = (UST*)alloc(LN_BYTES);
    float* combine = (float*)alloc(8192 * 8 * 4);
    float* entacc  = (float*)alloc(256);
    char*  BIG = alloc(8192L * 3072 * 4);     // Sp (6x16MB) during attn; y/h1 later
    UST* OH = (UST*)alloc(8192L * 1024 * 2);  // attn out hi; later x3 bf16
    UST* OL = (UST*)alloc(8192L * 1024 * 2);
    if (off > ws_size) return;  // ws too small -> deliberate clean fail

    UST* Sp   = (UST*)BIG;      // [Qh|Ql|Kh|Kl|Vth|Vtl]
    UST* ybuf = (UST*)BIG;
    UST* h1   = (UST*)BIG;
    UST* x3h  = OH;

    // ---- weight prep (every call; ws is re-poisoned) ----
    auto nb = [](long n) { return (unsigned)((n + 255) / 256); };
    prep_t_kernel<<<dim3(48, 32), 256, 0, stream>>>(qkv_w, qkvWh, qkvWl, 3072, 1024);
    prep_t_kernel<<<dim3(16, 32), 256, 0, stream>>>(ao_w, aoWh, aoWl, 1024, 1024);
    for (int k = 0; k < 3; k++)
        prep_w_kernel<<<nb(1024L * 1024), 256, 0, stream>>>(conv_w + k, convCh, convCl,
                                                            1024, 3, 3072, 3072, k * 1024, 1024L * 1024);
    for (int e = 0; e < 8; e++)
        prep_t_kernel<<<dim3(16, 32), 256, 0, stream>>>(exp_w + (long)e * 1048576, expW + (long)e * 1048576,
                                                        nullptr, 1024, 1024);
    prep_t_kernel<<<dim3(64, 32), 256, 0, stream>>>(ff_w1, ff1W, nullptr, 4096, 1024);
    prep_t_kernel<<<dim3(16, 128), 256, 0, stream>>>(ff_w2, ff2W, nullptr, 1024, 4096);

    ln_pad_kernel<<<8, 256, 0, stream>>>(LNh, LNl);
    hipMemsetAsync(entacc, 0, 4, stream);

    // ---- attention block ----
    ln_split_kernel<<<8192, 256, 0, stream>>>(x, ln1_g, ln1_b, LNh, LNl);
    gemm_bt_kernel<2, true, 0><<<dim3(24, 64), 256, 0, stream>>>(LNh, LNl, qkvWh, qkvWl, qkv_b, nullptr,
                                                                 nullptr, nullptr, Sp, 8192, 3072, 1024, 1024, 2, 4);
    attn_mfma_kernel<<<512, 256, 0, stream>>>(Sp, OH, OL);
    gemm_bt_kernel<0, true, 0><<<dim3(8, 64), 256, 0, stream>>>(OH, OL, aoWh, aoWl, ao_b, x,
                                                                out, nullptr, nullptr, 8192, 1024, 1024, 1024, 0, 0);
    // ---- dilated conv block: ONE fused GEMM, K=3072 (3 shifted segments) ----
    ln_split_kernel<<<8192, 256, 0, stream>>>(out, ln2_g, ln2_b, LNh, LNl);
    gemm_bt_kernel<0, true, 1024><<<dim3(8, 64), 256, 0, stream>>>(LNh, LNl, convCh, convCl, conv_b, out,
                                                                   out, nullptr, nullptr, 8192, 1024, 3072, 1024, 0, 4);
    // ---- MoE ----
    ln_split_kernel<<<8192, 256, 0, stream>>>(out, ln3_g, ln3_b, LNh, LNl);
    gate_kernel<<<2048, 256, 0, stream>>>(LNh, LNl, gate_w, gate_b, combine, entacc);
    ent_final_kernel<<<1, 1, 0, stream>>>(entacc, out + 8388608);
    for (int hh = 0; hh < 2; hh++) {
        gemm_bt_kernel<1, false, 0><<<dim3(32, 64), 256, 0, stream>>>(LNh, nullptr, expW + (long)hh * 4096 * 1024,
                                                                      nullptr, exp_b + hh * 4096, nullptr,
                                                                      nullptr, ybuf, nullptr, 8192, 4096, 1024, 1024, 2, 4);
        moe_combine_kernel<<<32768, 256, 0, stream>>>(ybuf, combine, out, hh);
    }
    // ---- FFN ----
    f32_to_bf16_kernel<<<8192, 256, 0, stream>>>(out, x3h);
    gemm_bt_kernel<1, false, 0><<<dim3(32, 64), 256, 0, stream>>>(x3h, nullptr, ff1W, nullptr, ff_b1, nullptr,
                                                                  nullptr, h1, nullptr, 8192, 4096, 1024, 1024, 0, 0);
    gemm_bt_kernel<0, false, 0><<<dim3(8, 64), 256, 0, stream>>>(h1, nullptr, ff2W, nullptr, ff_b2, out,
                                                                 out, nullptr, nullptr, 8192, 1024, 4096, 4096, 0, 0);
}

// Round 2
// 1542.202 us; speedup vs baseline: 1.0537x; 1.0302x over previous
//
#include <hip/hip_runtime.h>
#include <hip/hip_bf16.h>
#include <math.h>

// ============================================================================
// ImprovedTransformerBlock on MI355X.  R5: gemm_bt_kernel gets (a) counted
// vmcnt pipeline — raw s_barrier + s_waitcnt vmcnt(8/4), never drain-0 in the
// main loop (T4, the m218 lever); ds-reads hoisted before the WAR barrier so
// stage(t+2) issue overlaps the MFMA cluster; (b) XOR-swizzled LDS tiles:
// linear GLL dest + inverse-swizzled per-lane global source + swizzled read
// offset (rule #21 both-sides pattern) to kill the measured 1.26e7
// bank-conflict cycles/dispatch; (c) s_setprio(1) around the MFMA cluster.
// Numerics bit-identical to R4 (same MFMA order).
// Precision plan: pre-gate path bf16x2-split MFMA (fp32-grade, protects top-2
// routing); post-gate (experts, FFN) plain bf16 MFMA.
// ============================================================================

typedef unsigned short UST;
typedef unsigned int uint32;
typedef float f32x4 __attribute__((ext_vector_type(4)));
using s16x8 = __attribute__((ext_vector_type(8))) short;   // 8 bf16 = 4 VGPRs

#define DEV __device__ __forceinline__
#define MFMA16 __builtin_amdgcn_mfma_f32_16x16x32_bf16

// async global->LDS, 16 bytes/lane; lds dst is wave-uniform base + lane*16
#define GLL(g, l) __builtin_amdgcn_global_load_lds( \
    (const __attribute__((address_space(1))) unsigned int*)(g), \
    (__attribute__((address_space(3))) unsigned int*)(l), 16, 0, 0)

// raw sync primitives (counted vmcnt pipeline) — asm with memory clobber so
// compiler-generated ds_read/GLL cannot migrate across them.
#define BARRIER()  asm volatile("s_barrier" ::: "memory")
#define LGKM0()    asm volatile("s_waitcnt lgkmcnt(0)" ::: "memory")
#define VM0()      asm volatile("s_waitcnt vmcnt(0)" ::: "memory")

DEV UST f2bf(float f) {                       // round-to-nearest-even fp32->bf16
    uint32 u = __float_as_uint(f);
    u += 0x7FFFu + ((u >> 16) & 1u);
    return (UST)(u >> 16);
}
DEV float bf2f(UST h) { return __uint_as_float(((uint32)h) << 16); }
DEV float gelu_f(float x) { return 0.5f * x * (1.0f + erff(x * 0.7071067811865475f)); }

// ---------------------------------------------------------------------------
// LayerNorm -> split bf16 (hi/lo), conv-padded row layout: row(t)=t+2+4*(t>>12)
// ---------------------------------------------------------------------------
__global__ void ln_split_kernel(const float* __restrict__ x,
                                const float* __restrict__ g, const float* __restrict__ b,
                                UST* __restrict__ oh, UST* __restrict__ ol)
{
    const int t = blockIdx.x;
    const int tid = threadIdx.x;
    const float4 v = ((const float4*)(x + (long)t * 1024))[tid];
    float s = v.x + v.y + v.z + v.w;
    float q = v.x * v.x + v.y * v.y + v.z * v.z + v.w * v.w;
    for (int o = 32; o > 0; o >>= 1) { s += __shfl_xor(s, o, 64); q += __shfl_xor(q, o, 64); }
    __shared__ float ss[4], sq[4];
    const int wave = tid >> 6, lane = tid & 63;
    if (lane == 0) { ss[wave] = s; sq[wave] = q; }
    __syncthreads();
    s = ss[0] + ss[1] + ss[2] + ss[3];
    q = sq[0] + sq[1] + sq[2] + sq[3];
    const float mean = s * (1.0f / 1024.0f);
    const float var = q * (1.0f / 1024.0f) - mean * mean;
    const float rstd = 1.0f / sqrtf(var + 1e-5f);
    const long row = (long)t + 2 + 4 * (t >> 12);
    UST* ph = oh + row * 1024 + tid * 4;
    UST* pl = ol + row * 1024 + tid * 4;
    const float4 gg = ((const float4*)g)[tid];
    const float4 bb = ((const float4*)b)[tid];
    float vv[4] = { v.x, v.y, v.z, v.w };
    float gv[4] = { gg.x, gg.y, gg.z, gg.w };
    float bv[4] = { bb.x, bb.y, bb.z, bb.w };
#pragma unroll
    for (int j = 0; j < 4; j++) {
        float f = (vv[j] - mean) * rstd * gv[j] + bv[j];
        UST hi = f2bf(f);
        ph[j] = hi;
        pl[j] = f2bf(f - bf2f(hi));
    }
}

// zero the conv-pad rows {b*4100 + 0,1,4098,4099} of LNh/LNl
__global__ void ln_pad_kernel(UST* __restrict__ oh, UST* __restrict__ ol)
{
    const int blk = blockIdx.x;          // 8 blocks
    const int b = blk >> 2, rsel = blk & 3;
    const long row = (long)b * 4100 + (rsel < 2 ? rsel : 4096 + rsel);
    const int tid = threadIdx.x;
    *(ushort4*)(oh + row * 1024 + tid * 4) = make_ushort4(0, 0, 0, 0);
    *(ushort4*)(ol + row * 1024 + tid * 4) = make_ushort4(0, 0, 0, 0);
}

// ---------------------------------------------------------------------------
// Coalesced transpose prep: dst[n*K+k] = src[k*N+n], bf16 hi (+lo).
// ---------------------------------------------------------------------------
__global__ void prep_t_kernel(const float* __restrict__ src, UST* __restrict__ dh,
                              UST* __restrict__ dl, int N, int K)
{
    __shared__ float tile[32][65];
    const int k0 = blockIdx.y * 32, n0 = blockIdx.x * 64;
    const int t = threadIdx.x;
    const int nn = t & 63, kk = t >> 6;
#pragma unroll
    for (int i = 0; i < 8; i++)
        tile[kk + i * 4][nn] = src[(long)(k0 + kk + i * 4) * N + n0 + nn];
    __syncthreads();
    const int kw = (t & 7) * 4;
#pragma unroll
    for (int pass = 0; pass < 2; pass++) {
        const int nw = (t >> 3) + pass * 32;
        UST hv[4], lv[4];
#pragma unroll
        for (int j = 0; j < 4; j++) {
            float v = tile[kw + j][nw];
            hv[j] = f2bf(v);
            lv[j] = f2bf(v - bf2f(hv[j]));
        }
        UST* bh = dh + (long)(n0 + nw) * K + k0 + kw;
        *(ushort4*)bh = make_ushort4(hv[0], hv[1], hv[2], hv[3]);
        if (dl) {
            UST* bl = dl + (long)(n0 + nw) * K + k0 + kw;
            *(ushort4*)bl = make_ushort4(lv[0], lv[1], lv[2], lv[3]);
        }
    }
}

// conv taps into concatenated B: dst[n*dstK + dstOff + k] = src[k*sr + n*sc]
__global__ void prep_w_kernel(const float* __restrict__ src, UST* __restrict__ dh,
                              UST* __restrict__ dl, int K, long sr, long sc,
                              int dstK, int dstOff, long total)
{
    long gid = (long)blockIdx.x * 256 + threadIdx.x;
    if (gid >= total) return;
    long n = gid / K, k = gid - n * K;
    float v = src[k * sr + n * sc];
    UST hi = f2bf(v);
    long di = n * dstK + dstOff + k;
    dh[di] = hi;
    if (dl) dl[di] = f2bf(v - bf2f(hi));
}

// ---------------------------------------------------------------------------
// GEMM: C[M,N] = A[M,K] * B^T[N,K]  (bf16, fp32 accum, MFMA 16x16x32)
// 128x128 tile, BK=32, 256 threads, global_load_lds(16B) staging.
// R5 pipeline (per 32-K tile, 2x unrolled for compile-time LDS bases):
//   s_waitcnt vmcnt(8|4)   own cur-tile GLLs landed (next tile stays in flight)
//   s_barrier              everyone's cur-tile landed
//   ds_read all frags      cur tile -> regs
//   lgkmcnt(0); s_barrier  all waves' reads done -> cur buf reusable (WAR)
//   stage(t+2 -> cur buf)  GLL issue overlaps MFMA
//   setprio(1) MFMA* setprio(0)
// Tail peels the last two tiles with vmcnt(8|4) then vmcnt(0).
// LDS XOR swizzle: physical = logical ^ ((row&7)<<4) bytes.  GLL dest stays
// linear; the per-lane GLOBAL source carries the inverse permutation
// (loop-invariant), reads use swizzled offset (lm*32+lq*8)^((lm&7)<<3) USTs.
// SPLIT: A=Ah+Al, B=Bh+Bl -> AhBh + AhBl + AlBh (fp32-grade).
// A row stride KA; A k-offset = k0 + (k0>>10)*ASHIFT (conv seg trick: segment
// s reads +2048 elements = +2 rows -> tap s hits row t+2s).
// EPI 0: Cf = acc(+bias)(+resid) fp32. EPI 1: Cb = bf16(gelu(acc+bias)).
// EPI 2: scatter split bf16 into Sp = [Qh|Ql|Kh|Kl|Vth|Vtl] (attention prep).
// ---------------------------------------------------------------------------
template<int EPI, bool SPLIT, int ASHIFT>
__global__ __launch_bounds__(256)
void gemm_bt_kernel(const UST* __restrict__ Ah, const UST* __restrict__ Al,
                    const UST* __restrict__ Bh, const UST* __restrict__ Bl,
                    const float* __restrict__ bias, const float* __restrict__ resid,
                    float* __restrict__ Cf, UST* __restrict__ Cb, UST* __restrict__ Sp,
                    int M, int N, int K, int KA, int rb, int radd)
{
    constexpr int ABUF = (SPLIT ? 2 : 1) * 4096;   // USTs per k-tile buffer
    __shared__ UST sA[2 * ABUF];
    __shared__ UST sB[2 * ABUF];
    const int tid = threadIdx.x;
    const int lane = tid & 63;
    const int wv = __builtin_amdgcn_readfirstlane(tid >> 6);
    const int wr = wv >> 1, wc = wv & 1;
    const int lm = lane & 15, lq = lane >> 4;
    const long m0 = (long)blockIdx.y * 128, n0 = (long)blockIdx.x * 128;

    // ---- staging source with inverse swizzle (write side of rule #21) ----
    // physical slot of this lane within a 16-row GLL chunk: row rp, 16B-col cp
    const int rp = lane >> 2, cp = lane & 3;
    const int rl0 = (rp ^ (rp >> 2)) & 1;                 // logical row bit0
    const int lrS = (rp & 14) | rl0;                      // logical row in chunk
    const int c1 = ((cp >> 1) ^ (rp >> 1)) & 1;
    const int c0 = (cp ^ rl0) & 1;
    const int lcS = (c1 * 2 + c0) * 8;                    // logical k-elem offset
    const int rA0 = wv * 32 + lrS, rA1 = wv * 32 + 16 + lrS;
    const long mtop = m0 >> 12;              // tiles never straddle 4096 rows
    const UST* gA0 = Ah + (m0 + rA0 + rb + (long)radd * mtop) * KA + lcS;
    const UST* gA1 = Ah + (m0 + rA1 + rb + (long)radd * mtop) * KA + lcS;
    const UST* gB0 = Bh + (n0 + rA0) * K + lcS;
    const UST* gB1 = Bh + (n0 + rA1) * K + lcS;
    const UST* gA0l = SPLIT ? (Al + (m0 + rA0 + rb + (long)radd * mtop) * KA + lcS) : nullptr;
    const UST* gA1l = SPLIT ? (Al + (m0 + rA1 + rb + (long)radd * mtop) * KA + lcS) : nullptr;
    const UST* gB0l = SPLIT ? (Bl + (n0 + rA0) * K + lcS) : nullptr;
    const UST* gB1l = SPLIT ? (Bl + (n0 + rA1) * K + lcS) : nullptr;

    // read-side swizzled lane offset (UST units), loop-invariant
    const int loff = (lm * 32 + lq * 8) ^ ((lm & 7) << 3);

    f32x4 acc[4][4] = {};
    s16x8 ah[4], bh[4], al[4], bl[4];

    // stage k-tile kk into buffer with per-wave bases dA/dB (wave-uniform)
    auto stage = [&](int kk, UST* dA, UST* dB) {
        const long aoff = ASHIFT ? (long)kk + (long)(kk >> 10) * ASHIFT : (long)kk;
        GLL(gA0 + aoff, dA); GLL(gA1 + aoff, dA + 512);
        GLL(gB0 + kk, dB); GLL(gB1 + kk, dB + 512);
        if (SPLIT) {
            GLL(gA0l + aoff, dA + 4096); GLL(gA1l + aoff, dA + 512 + 4096);
            GLL(gB0l + kk, dB + 4096); GLL(gB1l + kk, dB + 512 + 4096);
        }
    };
    // load all fragments of the staged tile at LDS bases cA/cB
    auto loads = [&](const UST* cA, const UST* cB) {
#pragma unroll
        for (int i = 0; i < 4; i++) {
            ah[i] = *(const s16x8*)&cA[(wr * 64 + i * 16) * 32 + loff];
            bh[i] = *(const s16x8*)&cB[(wc * 64 + i * 16) * 32 + loff];
        }
        if constexpr (SPLIT) {
#pragma unroll
            for (int i = 0; i < 4; i++) {
                al[i] = *(const s16x8*)&cA[4096 + (wr * 64 + i * 16) * 32 + loff];
                bl[i] = *(const s16x8*)&cB[4096 + (wc * 64 + i * 16) * 32 + loff];
            }
        }
    };
    auto mfma_all = [&]() {
        __builtin_amdgcn_s_setprio(1);
#pragma unroll
        for (int i = 0; i < 4; i++)
#pragma unroll
            for (int j = 0; j < 4; j++)
                acc[i][j] = MFMA16(ah[i], bh[j], acc[i][j], 0, 0, 0);
        if constexpr (SPLIT) {
#pragma unroll
            for (int i = 0; i < 4; i++)
#pragma unroll
                for (int j = 0; j < 4; j++) {
                    acc[i][j] = MFMA16(ah[i], bl[j], acc[i][j], 0, 0, 0);
                    acc[i][j] = MFMA16(al[i], bh[j], acc[i][j], 0, 0, 0);
                }
        }
        __builtin_amdgcn_s_setprio(0);
    };
    auto vm_cur = [&]() {
        if constexpr (SPLIT) asm volatile("s_waitcnt vmcnt(8)" ::: "memory");
        else                 asm volatile("s_waitcnt vmcnt(4)" ::: "memory");
    };

    UST* wA0 = &sA[wv * 1024];               // wave-uniform LDS bases
    UST* wB0 = &sB[wv * 1024];
    UST* wA1 = &sA[ABUF + wv * 1024];
    UST* wB1 = &sB[ABUF + wv * 1024];

    stage(0, wA0, wB0);                      // tile 0 -> buf0
    stage(32, wA1, wB1);                     // tile 1 -> buf1
    for (int k0 = 0; k0 + 64 < K; k0 += 64) {
        vm_cur(); BARRIER();                 // tile k0/32 (buf0) fully in LDS
        loads(&sA[0], &sB[0]);
        LGKM0(); BARRIER();                  // all waves done reading buf0
        stage(k0 + 64, wA0, wB0);            // overlap with MFMA below
        mfma_all();
        vm_cur(); BARRIER();                 // tile k0/32+1 (buf1) in LDS
        loads(&sA[ABUF], &sB[ABUF]);
        LGKM0(); BARRIER();
        stage(k0 + 96, wA1, wB1);
        mfma_all();
    }
    // tail: tiles T-2 (buf0) and T-1 (buf1), no more staging
    vm_cur(); BARRIER();
    loads(&sA[0], &sB[0]);
    mfma_all();
    VM0(); BARRIER();
    loads(&sA[ABUF], &sB[ABUF]);
    mfma_all();

    // C/D layout (m89/m91-verified): col = lane&15, row = (lane>>4)*4 + reg
    const long SZ = 8388608L;
    const int colbase = (int)n0 + wc * 64;          // wave-uniform
    const int part = colbase >> 10;                 // EPI2: 0=Q,1=K,2=V
    const int hh = (colbase & 1023) >> 6;
    UST* H = (EPI == 2) ? (Sp + (long)part * 2 * SZ) : nullptr;
    UST* Lo = (EPI == 2) ? (H + SZ) : nullptr;
#pragma unroll
    for (int i = 0; i < 4; i++) {
#pragma unroll
        for (int j = 0; j < 4; j++) {
#pragma unroll
            for (int r = 0; r < 4; r++) {
                const long grow = m0 + wr * 64 + i * 16 + lq * 4 + r;
                const long gcol = n0 + wc * 64 + j * 16 + lm;
                float v = acc[i][j][r];
                if (bias) v += bias[gcol];
                if (EPI == 0) {
                    const long idx = grow * N + gcol;
                    if (resid) v += resid[idx];
                    Cf[idx] = v;
                } else if (EPI == 1) {
                    Cb[grow * N + gcol] = f2bf(gelu_f(v));
                } else {
                    const int d = j * 16 + lm;      // col within head
                    long idx;
                    if (part < 2) {
                        idx = ((long)hh * 8192 + grow) * 64 + d;
                    } else {
                        const int bb = (int)(grow >> 12), ww = (int)((grow >> 8) & 15),
                                  tt = (int)(grow & 255);
                        idx = ((long)((bb * 16 + ww) * 16 + hh)) * 16384 + (long)d * 256 + tt;
                    }
                    UST hi = f2bf(v);
                    H[idx] = hi;
                    Lo[idx] = f2bf(v - bf2f(hi));
                }
            }
        }
    }
}

// ---------------------------------------------------------------------------
// MFMA windowed attention (split-bf16, fp32-grade). Block = (b,win,head),
// 4 waves; wave owns 64 q-rows, iterates 8 k-chunks of 32 keys.
// S = QhKh+QhKl+QlKh (fp32 acc) -> P = exp(S/8) fp32 (scores bounded, no max)
// -> P split hi/lo through per-wave LDS (stride 40, 16B-aligned frag reads)
// -> O += PhVh+PhVl+PlVh.  l accumulated via cross-lane xor-reduce.
// Q frags live in registers whole kernel; K/V frags read from global (L2).
// ---------------------------------------------------------------------------
__global__ __launch_bounds__(256, 2)
void attn_mfma_kernel(const UST* __restrict__ Sp, UST* __restrict__ oh, UST* __restrict__ ol)
{
    __shared__ UST sPh[4 * 64 * 40];
    __shared__ UST sPl[4 * 64 * 40];
    const long SZ = 8388608L;
    const UST* Qh = Sp;
    const UST* Ql = Sp + SZ;
    const UST* Kh = Sp + 2 * SZ;
    const UST* Kl = Sp + 3 * SZ;
    const UST* Vth = Sp + 4 * SZ;
    const UST* Vtl = Sp + 5 * SZ;
    const int blk = blockIdx.x;
    const int h = blk & 15, w = (blk >> 4) & 15, b = blk >> 8;
    const long tok0 = (long)b * 4096 + w * 256;
    const int tid = threadIdx.x;
    const int lane = tid & 63;
    const int wv = tid >> 6;
    const int lm = lane & 15, lq = lane >> 4;

    // Q fragments (A-operand: m=lane&15, k=(lane>>4)*8+j), resident all kernel
    const long qrow0 = (long)h * 8192 + tok0 + wv * 64;
    s16x8 qhf[4][2], qlf[4][2];
#pragma unroll
    for (int mt = 0; mt < 4; mt++)
#pragma unroll
        for (int ks = 0; ks < 2; ks++) {
            const long o = (qrow0 + mt * 16 + lm) * 64 + ks * 32 + lq * 8;
            qhf[mt][ks] = *(const s16x8*)(Qh + o);
            qlf[mt][ks] = *(const s16x8*)(Ql + o);
        }
    const long krow0 = (long)h * 8192 + tok0;
    const long vbase = (long)blk * 16384;

    f32x4 Oacc[4][4] = {};
    float lsum[4][4] = {};
    UST* myPh = &sPh[wv * 2560];
    UST* myPl = &sPl[wv * 2560];

    for (int c = 0; c < 8; c++) {
        const int kt = c * 32;
        // ---- S = Q K^T (64q x 32k), split 3-product ----
        f32x4 S[4][2] = {};
#pragma unroll
        for (int nt = 0; nt < 2; nt++)
#pragma unroll
            for (int ks = 0; ks < 2; ks++) {
                const long o = (krow0 + kt + nt * 16 + lm) * 64 + ks * 32 + lq * 8;
                s16x8 khf = *(const s16x8*)(Kh + o);
                s16x8 klf = *(const s16x8*)(Kl + o);
#pragma unroll
                for (int mt = 0; mt < 4; mt++) {
                    S[mt][nt] = MFMA16(qhf[mt][ks], khf, S[mt][nt], 0, 0, 0);
                    S[mt][nt] = MFMA16(qhf[mt][ks], klf, S[mt][nt], 0, 0, 0);
                    S[mt][nt] = MFMA16(qlf[mt][ks], khf, S[mt][nt], 0, 0, 0);
                }
            }
        // ---- P = exp(S/8); l partial; write P split to LDS ----
#pragma unroll
        for (int mt = 0; mt < 4; mt++)
#pragma unroll
            for (int r = 0; r < 4; r++) {
                float p0 = __expf(S[mt][0][r] * 0.125f);
                float p1 = __expf(S[mt][1][r] * 0.125f);
                float part = p0 + p1;
                part += __shfl_xor(part, 1, 64);
                part += __shfl_xor(part, 2, 64);
                part += __shfl_xor(part, 4, 64);
                part += __shfl_xor(part, 8, 64);
                lsum[mt][r] += part;
                const int q = mt * 16 + lq * 4 + r;
                UST h0 = f2bf(p0), h1 = f2bf(p1);
                myPh[q * 40 + lm] = h0;
                myPh[q * 40 + 16 + lm] = h1;
                myPl[q * 40 + lm] = f2bf(p0 - bf2f(h0));
                myPl[q * 40 + 16 + lm] = f2bf(p1 - bf2f(h1));
            }
        // ---- O += P V (P from LDS A-frags, V^T from global B-frags) ----
#pragma unroll
        for (int mt = 0; mt < 4; mt++) {
            s16x8 phf = *(const s16x8*)(myPh + (mt * 16 + lm) * 40 + lq * 8);
            s16x8 plf = *(const s16x8*)(myPl + (mt * 16 + lm) * 40 + lq * 8);
#pragma unroll
            for (int dt = 0; dt < 4; dt++) {
                const long o = vbase + (dt * 16 + lm) * 256 + kt + lq * 8;
                s16x8 vhf = *(const s16x8*)(Vth + o);
                s16x8 vlf = *(const s16x8*)(Vtl + o);
                Oacc[mt][dt] = MFMA16(phf, vhf, Oacc[mt][dt], 0, 0, 0);
                Oacc[mt][dt] = MFMA16(phf, vlf, Oacc[mt][dt], 0, 0, 0);
                Oacc[mt][dt] = MFMA16(plf, vhf, Oacc[mt][dt], 0, 0, 0);
            }
        }
    }
    // ---- normalize + write split bf16 ----
#pragma unroll
    for (int mt = 0; mt < 4; mt++)
#pragma unroll
        for (int r = 0; r < 4; r++) {
            const float inv = 1.0f / lsum[mt][r];
            const long tok = tok0 + wv * 64 + mt * 16 + lq * 4 + r;
            UST* po = oh + tok * 1024 + h * 64;
            UST* plo = ol + tok * 1024 + h * 64;
#pragma unroll
            for (int dt = 0; dt < 4; dt++) {
                float f = Oacc[mt][dt][r] * inv;
                UST hv = f2bf(f);
                po[dt * 16 + lm] = hv;
                plo[dt * 16 + lm] = f2bf(f - bf2f(hv));
            }
        }
}

// ---------------------------------------------------------------------------
// Gate: logits (hi+lo fp32-grade), softmax, entropy, top-2 -> combine weights.
// ---------------------------------------------------------------------------
__global__ void gate_kernel(const UST* __restrict__ lnh, const UST* __restrict__ lnl,
                            const float* __restrict__ gw, const float* __restrict__ gb,
                            float* __restrict__ combine, float* __restrict__ ent_acc)
{
    const int tid = threadIdx.x;
    const int t = blockIdx.x * 4 + (tid >> 6);
    const int lane = tid & 63;
    const long row = (long)t + 2 + 4 * (t >> 12);
    const UST* ph = lnh + row * 1024;
    const UST* pl = lnl + row * 1024;
    float acc[8] = { 0, 0, 0, 0, 0, 0, 0, 0 };
    for (int c = 0; c < 16; c++) {
        int d = c * 64 + lane;
        float xv = bf2f(ph[d]) + bf2f(pl[d]);
        const float* wr = gw + (long)d * 8;
#pragma unroll
        for (int e = 0; e < 8; e++) acc[e] += xv * wr[e];
    }
#pragma unroll
    for (int e = 0; e < 8; e++)
        for (int o = 32; o > 0; o >>= 1) acc[e] += __shfl_xor(acc[e], o, 64);
    if (lane == 0) {
        float lg[8], p[8];
        float mx = -1e30f;
        for (int e = 0; e < 8; e++) { lg[e] = acc[e] + gb[e]; mx = fmaxf(mx, lg[e]); }
        float sum = 0;
        for (int e = 0; e < 8; e++) { p[e] = expf(lg[e] - mx); sum += p[e]; }
        float inv = 1.0f / sum;
        float ent = 0;
        for (int e = 0; e < 8; e++) { p[e] *= inv; ent -= p[e] * logf(p[e] + 1e-10f); }
        int i1 = 0; float v1 = -1e30f;
        for (int e = 0; e < 8; e++) if (p[e] > v1) { v1 = p[e]; i1 = e; }
        int i2 = 0; float v2 = -1e30f;
        for (int e = 0; e < 8; e++) if (e != i1 && p[e] > v2) { v2 = p[e]; i2 = e; }
        float inv2 = 1.0f / (v1 + v2);
        float cw[8] = { 0, 0, 0, 0, 0, 0, 0, 0 };
        cw[i1] = v1 * inv2; cw[i2] = v2 * inv2;
        float* co = combine + (long)t * 8;
        for (int e = 0; e < 8; e++) co[e] = cw[e];
        atomicAdd(ent_acc, ent);
    }
}

// out[t,f] += sum_j combine[t, half*4+j] * y[t, j*1024+f]
__global__ void moe_combine_kernel(const UST* __restrict__ y, const float* __restrict__ combine,
                                   float* __restrict__ out, int halfsel)
{
    const long gid = (long)blockIdx.x * 256 + threadIdx.x;
    const int t = (int)(gid >> 10), f = (int)(gid & 1023);
    const float* cw = combine + (long)t * 8 + halfsel * 4;
    const UST* yp = y + (long)t * 4096 + f;
    float s = cw[0] * bf2f(yp[0]) + cw[1] * bf2f(yp[1024])
            + cw[2] * bf2f(yp[2048]) + cw[3] * bf2f(yp[3072]);
    out[gid] += s;
}

__global__ void f32_to_bf16_kernel(const float* __restrict__ in, UST* __restrict__ out)
{
    long gid = ((long)blockIdx.x * 256 + threadIdx.x) * 4;
    float4 v = *(const float4*)(in + gid);
    out[gid] = f2bf(v.x); out[gid + 1] = f2bf(v.y);
    out[gid + 2] = f2bf(v.z); out[gid + 3] = f2bf(v.w);
}

__global__ void ent_final_kernel(const float* __restrict__ acc, float* __restrict__ out)
{
    out[0] = 0.1f * acc[0] * (1.0f / 8192.0f);
}

// ===========================================================================
extern "C" void kernel_launch(void* const* d_in, const int* in_sizes, int n_in,
                              void* d_out_, int out_size, void* d_ws, size_t ws_size,
                              hipStream_t stream)
{
    const float* x      = (const float*)d_in[0];
    const float* ln1_g  = (const float*)d_in[1];
    const float* ln1_b  = (const float*)d_in[2];
    const float* qkv_w  = (const float*)d_in[3];
    const float* qkv_b  = (const float*)d_in[4];
    const float* ao_w   = (const float*)d_in[5];
    const float* ao_b   = (const float*)d_in[6];
    const float* ln2_g  = (const float*)d_in[7];
    const float* ln2_b  = (const float*)d_in[8];
    const float* conv_w = (const float*)d_in[9];
    const float* conv_b = (const float*)d_in[10];
    const float* ln3_g  = (const float*)d_in[11];
    const float* ln3_b  = (const float*)d_in[12];
    const float* gate_w = (const float*)d_in[13];
    const float* gate_b = (const float*)d_in[14];
    const float* exp_w  = (const float*)d_in[15];
    const float* exp_b  = (const float*)d_in[16];
    const float* ff_w1  = (const float*)d_in[17];
    const float* ff_b1  = (const float*)d_in[18];
    const float* ff_w2  = (const float*)d_in[19];
    const float* ff_b2  = (const float*)d_in[20];
    float* out = (float*)d_out_;

    char* ws = (char*)d_ws;
    size_t off = 0;
    auto alloc = [&](size_t bytes) -> char* {
        char* p = ws + off;
        off += (bytes + 255) & ~(size_t)255;
        return p;
    };
    UST* qkvWh = (UST*)alloc(3072 * 1024 * 2);
    UST* qkvWl = (UST*)alloc(3072 * 1024 * 2);
    UST* aoWh  = (UST*)alloc(1024 * 1024 * 2);
    UST* aoWl  = (UST*)alloc(1024 * 1024 * 2);
    UST* convCh = (UST*)alloc(1024L * 3072 * 2);   // [n=1024][k=3072] concat taps
    UST* convCl = (UST*)alloc(1024L * 3072 * 2);
    UST* expW  = (UST*)alloc(8192L * 1024 * 2);
    UST* ff1W  = (UST*)alloc(4096L * 1024 * 2);
    UST* ff2W  = (UST*)alloc(4096L * 1024 * 2);
    const size_t LN_BYTES = 8200L * 1024 * 2;
    UST* LNh = (UST*)alloc(LN_BYTES);
    UST* LNl = (UST*)alloc(LN_BYTES);
    float* combine = (float*)alloc(8192 * 8 * 4);
    float* entacc  = (float*)alloc(256);
    char*  BIG = alloc(8192L * 3072 * 4);     // Sp (6x16MB) during attn; y/h1 later
    UST* OH = (UST*)alloc(8192L * 1024 * 2);  // attn out hi; later x3 bf16
    UST* OL = (UST*)alloc(8192L * 1024 * 2);
    if (off > ws_size) return;  // ws too small -> deliberate clean fail

    UST* Sp   = (UST*)BIG;      // [Qh|Ql|Kh|Kl|Vth|Vtl]
    UST* ybuf = (UST*)BIG;
    UST* h1   = (UST*)BIG;
    UST* x3h  = OH;

    // ---- weight prep (every call; ws is re-poisoned) ----
    auto nb = [](long n) { return (unsigned)((n + 255) / 256); };
    prep_t_kernel<<<dim3(48, 32), 256, 0, stream>>>(qkv_w, qkvWh, qkvWl, 3072, 1024);
    prep_t_kernel<<<dim3(16, 32), 256, 0, stream>>>(ao_w, aoWh, aoWl, 1024, 1024);
    for (int k = 0; k < 3; k++)
        prep_w_kernel<<<nb(1024L * 1024), 256, 0, stream>>>(conv_w + k, convCh, convCl,
                                                            1024, 3, 3072, 3072, k * 1024, 1024L * 1024);
    for (int e = 0; e < 8; e++)
        prep_t_kernel<<<dim3(16, 32), 256, 0, stream>>>(exp_w + (long)e * 1048576, expW + (long)e * 1048576,
                                                        nullptr, 1024, 1024);
    prep_t_kernel<<<dim3(64, 32), 256, 0, stream>>>(ff_w1, ff1W, nullptr, 4096, 1024);
    prep_t_kernel<<<dim3(16, 128), 256, 0, stream>>>(ff_w2, ff2W, nullptr, 1024, 4096);

    ln_pad_kernel<<<8, 256, 0, stream>>>(LNh, LNl);
    hipMemsetAsync(entacc, 0, 4, stream);

    // ---- attention block ----
    ln_split_kernel<<<8192, 256, 0, stream>>>(x, ln1_g, ln1_b, LNh, LNl);
    gemm_bt_kernel<2, true, 0><<<dim3(24, 64), 256, 0, stream>>>(LNh, LNl, qkvWh, qkvWl, qkv_b, nullptr,
                                                                 nullptr, nullptr, Sp, 8192, 3072, 1024, 1024, 2, 4);
    attn_mfma_kernel<<<512, 256, 0, stream>>>(Sp, OH, OL);
    gemm_bt_kernel<0, true, 0><<<dim3(8, 64), 256, 0, stream>>>(OH, OL, aoWh, aoWl, ao_b, x,
                                                                out, nullptr, nullptr, 8192, 1024, 1024, 1024, 0, 0);
    // ---- dilated conv block: ONE fused GEMM, K=3072 (3 shifted segments) ----
    ln_split_kernel<<<8192, 256, 0, stream>>>(out, ln2_g, ln2_b, LNh, LNl);
    gemm_bt_kernel<0, true, 1024><<<dim3(8, 64), 256, 0, stream>>>(LNh, LNl, convCh, convCl, conv_b, out,
                                                                   out, nullptr, nullptr, 8192, 1024, 3072, 1024, 0, 4);
    // ---- MoE ----
    ln_split_kernel<<<8192, 256, 0, stream>>>(out, ln3_g, ln3_b, LNh, LNl);
    gate_kernel<<<2048, 256, 0, stream>>>(LNh, LNl, gate_w, gate_b, combine, entacc);
    ent_final_kernel<<<1, 1, 0, stream>>>(entacc, out + 8388608);
    for (int hh = 0; hh < 2; hh++) {
        gemm_bt_kernel<1, false, 0><<<dim3(32, 64), 256, 0, stream>>>(LNh, nullptr, expW + (long)hh * 4096 * 1024,
                                                                      nullptr, exp_b + hh * 4096, nullptr,
                                                                      nullptr, ybuf, nullptr, 8192, 4096, 1024, 1024, 2, 4);
        moe_combine_kernel<<<32768, 256, 0, stream>>>(ybuf, combine, out, hh);
    }
    // ---- FFN ----
    f32_to_bf16_kernel<<<8192, 256, 0, stream>>>(out, x3h);
    gemm_bt_kernel<1, false, 0><<<dim3(32, 64), 256, 0, stream>>>(x3h, nullptr, ff1W, nullptr, ff_b1, nullptr,
                                                                  nullptr, h1, nullptr, 8192, 4096, 1024, 1024, 0, 0);
    gemm_bt_kernel<0, false, 0><<<dim3(8, 64), 256, 0, stream>>>(h1, nullptr, ff2W, nullptr, ff_b2, out,
                                                                 out, nullptr, nullptr, 8192, 1024, 4096, 4096, 0, 0);
}

// Round 3
// 1519.764 us; speedup vs baseline: 1.0693x; 1.0148x over previous
//
#include <hip/hip_runtime.h>
#include <hip/hip_bf16.h>
#include <math.h>

// ============================================================================
// ImprovedTransformerBlock on MI355X.  R6: gemm_bt_kernel ported to a
// 4-phase-per-tile interleaved schedule (T3+T4+T5 together, per the catalog's
// regime gate): BM=256 x BN=128, 8 waves (4Mx2N), 512 threads, triple-buffered
// LDS (3 x 48 KB), 6 GLL/wave/tile, boundary s_waitcnt vmcnt(6) (never 0 in
// steady state).  Each phase: {ds_read B-frag pair (+A frags in ph0) | 2 GLL
// for tile t+2 | barrier | lgkmcnt(0) | setprio(1) MFMA-cluster setprio(0) |
// barrier}.  LDS laid out as four [rows][32k] sub-blocks (64-B row stride ->
// contiguous 1KB/wave reads, conflict-free; R5's swizzle reverted as null).
// Numerics: per-element accumulation order unchanged vs R5.
// Precision plan: pre-gate path bf16x2-split MFMA (fp32-grade, protects top-2
// routing); post-gate (experts, FFN) plain bf16 MFMA.
// ============================================================================

typedef unsigned short UST;
typedef unsigned int uint32;
typedef float f32x4 __attribute__((ext_vector_type(4)));
using s16x8 = __attribute__((ext_vector_type(8))) short;   // 8 bf16 = 4 VGPRs

#define DEV __device__ __forceinline__
#define MFMA16 __builtin_amdgcn_mfma_f32_16x16x32_bf16

// async global->LDS, 16 bytes/lane; lds dst is wave-uniform base + lane*16
#define GLL(g, l) __builtin_amdgcn_global_load_lds( \
    (const __attribute__((address_space(1))) unsigned int*)(g), \
    (__attribute__((address_space(3))) unsigned int*)(l), 16, 0, 0)

// raw sync primitives — asm with memory clobber so compiler-generated
// ds_read/GLL cannot migrate across them.
#define BARRIER()  asm volatile("s_barrier" ::: "memory")
#define LGKM0()    asm volatile("s_waitcnt lgkmcnt(0)" ::: "memory")
#define VM0()      asm volatile("s_waitcnt vmcnt(0)" ::: "memory")
#define VMN6()     asm volatile("s_waitcnt vmcnt(6)" ::: "memory")

DEV UST f2bf(float f) {                       // round-to-nearest-even fp32->bf16
    uint32 u = __float_as_uint(f);
    u += 0x7FFFu + ((u >> 16) & 1u);
    return (UST)(u >> 16);
}
DEV float bf2f(UST h) { return __uint_as_float(((uint32)h) << 16); }
DEV float gelu_f(float x) { return 0.5f * x * (1.0f + erff(x * 0.7071067811865475f)); }

// ---------------------------------------------------------------------------
// LayerNorm -> split bf16 (hi/lo), conv-padded row layout: row(t)=t+2+4*(t>>12)
// ---------------------------------------------------------------------------
__global__ void ln_split_kernel(const float* __restrict__ x,
                                const float* __restrict__ g, const float* __restrict__ b,
                                UST* __restrict__ oh, UST* __restrict__ ol)
{
    const int t = blockIdx.x;
    const int tid = threadIdx.x;
    const float4 v = ((const float4*)(x + (long)t * 1024))[tid];
    float s = v.x + v.y + v.z + v.w;
    float q = v.x * v.x + v.y * v.y + v.z * v.z + v.w * v.w;
    for (int o = 32; o > 0; o >>= 1) { s += __shfl_xor(s, o, 64); q += __shfl_xor(q, o, 64); }
    __shared__ float ss[4], sq[4];
    const int wave = tid >> 6, lane = tid & 63;
    if (lane == 0) { ss[wave] = s; sq[wave] = q; }
    __syncthreads();
    s = ss[0] + ss[1] + ss[2] + ss[3];
    q = sq[0] + sq[1] + sq[2] + sq[3];
    const float mean = s * (1.0f / 1024.0f);
    const float var = q * (1.0f / 1024.0f) - mean * mean;
    const float rstd = 1.0f / sqrtf(var + 1e-5f);
    const long row = (long)t + 2 + 4 * (t >> 12);
    UST* ph = oh + row * 1024 + tid * 4;
    UST* pl = ol + row * 1024 + tid * 4;
    const float4 gg = ((const float4*)g)[tid];
    const float4 bb = ((const float4*)b)[tid];
    float vv[4] = { v.x, v.y, v.z, v.w };
    float gv[4] = { gg.x, gg.y, gg.z, gg.w };
    float bv[4] = { bb.x, bb.y, bb.z, bb.w };
#pragma unroll
    for (int j = 0; j < 4; j++) {
        float f = (vv[j] - mean) * rstd * gv[j] + bv[j];
        UST hi = f2bf(f);
        ph[j] = hi;
        pl[j] = f2bf(f - bf2f(hi));
    }
}

// zero the conv-pad rows {b*4100 + 0,1,4098,4099} of LNh/LNl
__global__ void ln_pad_kernel(UST* __restrict__ oh, UST* __restrict__ ol)
{
    const int blk = blockIdx.x;          // 8 blocks
    const int b = blk >> 2, rsel = blk & 3;
    const long row = (long)b * 4100 + (rsel < 2 ? rsel : 4096 + rsel);
    const int tid = threadIdx.x;
    *(ushort4*)(oh + row * 1024 + tid * 4) = make_ushort4(0, 0, 0, 0);
    *(ushort4*)(ol + row * 1024 + tid * 4) = make_ushort4(0, 0, 0, 0);
}

// ---------------------------------------------------------------------------
// Coalesced transpose prep: dst[n*K+k] = src[k*N+n], bf16 hi (+lo).
// ---------------------------------------------------------------------------
__global__ void prep_t_kernel(const float* __restrict__ src, UST* __restrict__ dh,
                              UST* __restrict__ dl, int N, int K)
{
    __shared__ float tile[32][65];
    const int k0 = blockIdx.y * 32, n0 = blockIdx.x * 64;
    const int t = threadIdx.x;
    const int nn = t & 63, kk = t >> 6;
#pragma unroll
    for (int i = 0; i < 8; i++)
        tile[kk + i * 4][nn] = src[(long)(k0 + kk + i * 4) * N + n0 + nn];
    __syncthreads();
    const int kw = (t & 7) * 4;
#pragma unroll
    for (int pass = 0; pass < 2; pass++) {
        const int nw = (t >> 3) + pass * 32;
        UST hv[4], lv[4];
#pragma unroll
        for (int j = 0; j < 4; j++) {
            float v = tile[kw + j][nw];
            hv[j] = f2bf(v);
            lv[j] = f2bf(v - bf2f(hv[j]));
        }
        UST* bh = dh + (long)(n0 + nw) * K + k0 + kw;
        *(ushort4*)bh = make_ushort4(hv[0], hv[1], hv[2], hv[3]);
        if (dl) {
            UST* bl = dl + (long)(n0 + nw) * K + k0 + kw;
            *(ushort4*)bl = make_ushort4(lv[0], lv[1], lv[2], lv[3]);
        }
    }
}

// conv taps into concatenated B: dst[n*dstK + dstOff + k] = src[k*sr + n*sc]
__global__ void prep_w_kernel(const float* __restrict__ src, UST* __restrict__ dh,
                              UST* __restrict__ dl, int K, long sr, long sc,
                              int dstK, int dstOff, long total)
{
    long gid = (long)blockIdx.x * 256 + threadIdx.x;
    if (gid >= total) return;
    long n = gid / K, k = gid - n * K;
    float v = src[k * sr + n * sc];
    UST hi = f2bf(v);
    long di = n * dstK + dstOff + k;
    dh[di] = hi;
    if (dl) dl[di] = f2bf(v - bf2f(hi));
}

// ---------------------------------------------------------------------------
// GEMM: C[M,N] = A[M,K] * B^T[N,K]  (bf16, fp32 accum, MFMA 16x16x32)
// R6 geometry: 256x128 tile, 8 waves (4Mx2N), per-wave 64x64, 512 threads.
// LDS: 3 buffers x 24576 USTs; buffer = subA0[256x32] | subA1[256x32] |
// subB0[128x32] | subB1[128x32].  split: A0/B0=hi, A1/B1=lo (BK=32);
// non-split: A0/B0=k[0,32), A1/B1=k[32,64) (BK=64).  Row stride 64 B ->
// wave frag reads are 1KB-contiguous (bank-conflict-free, no swizzle).
// Schedule per tile t (4 phases, j = C column-quadrant):
//   ph j: ds_read b0f/b1f[j] (+8 A frags if j==0); 2 GLL for tile t+2
//         (ph0: A0, ph1: A1, ph2: B); s_barrier; lgkmcnt(0);
//         setprio(1); 12(split)/8(plain) MFMA; setprio(0); s_barrier
//   boundary: vmcnt(6) [vmcnt(0) for last pair]; s_barrier; rotate buffers.
// Ledger: 6 GLL/wave/tile; prologue stages tiles 0,1 then vmcnt(6).
// WAR safe: buffer (t+2)%3 last read in tile t-1, drained by that tile's
// pre-MFMA lgkmcnt(0) which precedes the t-1 -> t boundary barrier.
// SPLIT: A=Ah+Al, B=Bh+Bl -> AhBh + AhBl + AlBh (fp32-grade), order per
// element identical to R5.  A row stride KA; A k-offset = kk + (kk>>10)*ASHIFT
// (conv seg trick).  EPI 0: Cf = acc(+bias)(+resid) fp32.  EPI 1: Cb =
// bf16(gelu(acc+bias)).  EPI 2: scatter split bf16 into Sp=[Qh|Ql|Kh|Kl|Vth|Vtl].
// ---------------------------------------------------------------------------
template<int EPI, bool SPLIT, int ASHIFT>
__global__ __launch_bounds__(512, 2)
void gemm_bt_kernel(const UST* __restrict__ Ah, const UST* __restrict__ Al,
                    const UST* __restrict__ Bh, const UST* __restrict__ Bl,
                    const float* __restrict__ bias, const float* __restrict__ resid,
                    float* __restrict__ Cf, UST* __restrict__ Cb, UST* __restrict__ Sp,
                    int M, int N, int K, int KA, int rb, int radd)
{
    constexpr int BK = SPLIT ? 32 : 64;
    constexpr int BUF = 24576;               // USTs per k-tile buffer (48 KB)
    __shared__ UST sL[3 * BUF];              // 144 KB
    const int tid = threadIdx.x;
    const int lane = tid & 63;
    const int wv = __builtin_amdgcn_readfirstlane(tid >> 6);   // 0..7
    const int wr = wv >> 1, wc = wv & 1;     // wave grid 4M x 2N
    const int lm = lane & 15, lq = lane >> 4;
    const long m0 = (long)blockIdx.y * 256, n0 = (long)blockIdx.x * 128;
    const long mtop = m0 >> 12;              // tiles never straddle 4096 rows

    // staging lane geometry: chunk = 16 rows x 32 k (1 KB);
    // lane covers row lane>>2, k-col (lane&3)*8
    const int lr = lane >> 2, lc = (lane & 3) * 8;
    const long arow = m0 + wv * 32 + lr + rb + (long)radd * mtop;
    const long brow = n0 + wv * 16 + lr;
    const UST* gA0 = Ah + arow * KA + lc;
    const UST* gA1 = SPLIT ? (Al + arow * KA + lc) : (Ah + arow * KA + 32 + lc);
    const UST* gB0 = Bh + brow * (long)K + lc;
    const UST* gB1 = SPLIT ? (Bl + brow * (long)K + lc) : (Bh + brow * (long)K + 32 + lc);

    const int rdo = lm * 32 + lq * 8;        // frag read offset within sub-block

    f32x4 acc[4][4] = {};
    s16x8 a0[4], a1[4];

    auto stageA0 = [&](long kk, UST* dst) {
        const long aoff = ASHIFT ? kk + (kk >> 10) * ASHIFT : kk;
        GLL(gA0 + aoff, dst + wv * 1024);
        GLL(gA0 + aoff + 16L * KA, dst + wv * 1024 + 512);
    };
    auto stageA1 = [&](long kk, UST* dst) {
        const long aoff = ASHIFT ? kk + (kk >> 10) * ASHIFT : kk;
        GLL(gA1 + aoff, dst + 8192 + wv * 1024);
        GLL(gA1 + aoff + 16L * KA, dst + 8192 + wv * 1024 + 512);
    };
    auto stageB = [&](long kk, UST* dst) {
        GLL(gB0 + kk, dst + 16384 + wv * 512);
        GLL(gB1 + kk, dst + 20480 + wv * 512);
    };

    UST* pb0 = &sL[0];                       // current tile
    UST* pb1 = &sL[BUF];                     // next tile
    UST* pb2 = &sL[2 * BUF];                 // staging target (t+2)

    const int NT = K / BK;
    stageA0(0, pb0); stageA1(0, pb0); stageB(0, pb0);
    stageA0(BK, pb1); stageA1(BK, pb1); stageB(BK, pb1);
    VMN6();                                   // tile 0's 6 GLLs landed
    BARRIER();

    for (int t = 0; t < NT; ++t) {
        const bool pf = (t + 2 < NT);
        const long kk2 = (long)(t + 2) * BK;
#pragma unroll
        for (int j = 0; j < 4; ++j) {
            s16x8 b0f = *(const s16x8*)&pb0[16384 + (wc * 64 + j * 16) * 32 + rdo];
            s16x8 b1f = *(const s16x8*)&pb0[20480 + (wc * 64 + j * 16) * 32 + rdo];
            if (j == 0) {
#pragma unroll
                for (int i = 0; i < 4; i++) {
                    a0[i] = *(const s16x8*)&pb0[(wr * 64 + i * 16) * 32 + rdo];
                    a1[i] = *(const s16x8*)&pb0[8192 + (wr * 64 + i * 16) * 32 + rdo];
                }
            }
            if (pf) {
                if (j == 0) stageA0(kk2, pb2);
                else if (j == 1) stageA1(kk2, pb2);
                else if (j == 2) stageB(kk2, pb2);
            }
            BARRIER();
            LGKM0();
            __builtin_amdgcn_s_setprio(1);
#pragma unroll
            for (int i = 0; i < 4; i++) {
                acc[i][j] = MFMA16(a0[i], b0f, acc[i][j], 0, 0, 0);
                if constexpr (SPLIT) {
                    acc[i][j] = MFMA16(a0[i], b1f, acc[i][j], 0, 0, 0);
                    acc[i][j] = MFMA16(a1[i], b0f, acc[i][j], 0, 0, 0);
                } else {
                    acc[i][j] = MFMA16(a1[i], b1f, acc[i][j], 0, 0, 0);
                }
            }
            __builtin_amdgcn_s_setprio(0);
            if (j < 3) BARRIER();
        }
        if (t + 1 < NT) {                    // boundary: next tile must be in LDS
            if (pf) { VMN6(); } else { VM0(); }
            BARRIER();
        }
        UST* tmp = pb0; pb0 = pb1; pb1 = pb2; pb2 = tmp;
    }

    // C/D layout (m89/m91-verified): col = lane&15, row = (lane>>4)*4 + reg
    const long SZ = 8388608L;
    const int colbase = (int)n0 + wc * 64;          // wave-uniform
    const int part = colbase >> 10;                 // EPI2: 0=Q,1=K,2=V
    const int hh = (colbase & 1023) >> 6;
    UST* H = (EPI == 2) ? (Sp + (long)part * 2 * SZ) : nullptr;
    UST* Lo = (EPI == 2) ? (H + SZ) : nullptr;
#pragma unroll
    for (int i = 0; i < 4; i++) {
#pragma unroll
        for (int j = 0; j < 4; j++) {
#pragma unroll
            for (int r = 0; r < 4; r++) {
                const long grow = m0 + wr * 64 + i * 16 + lq * 4 + r;
                const long gcol = n0 + wc * 64 + j * 16 + lm;
                float v = acc[i][j][r];
                if (bias) v += bias[gcol];
                if (EPI == 0) {
                    const long idx = grow * N + gcol;
                    if (resid) v += resid[idx];
                    Cf[idx] = v;
                } else if (EPI == 1) {
                    Cb[grow * N + gcol] = f2bf(gelu_f(v));
                } else {
                    const int d = j * 16 + lm;      // col within head
                    long idx;
                    if (part < 2) {
                        idx = ((long)hh * 8192 + grow) * 64 + d;
                    } else {
                        const int bb = (int)(grow >> 12), ww = (int)((grow >> 8) & 15),
                                  tt = (int)(grow & 255);
                        idx = ((long)((bb * 16 + ww) * 16 + hh)) * 16384 + (long)d * 256 + tt;
                    }
                    UST hi = f2bf(v);
                    H[idx] = hi;
                    Lo[idx] = f2bf(v - bf2f(hi));
                }
            }
        }
    }
}

// ---------------------------------------------------------------------------
// MFMA windowed attention (split-bf16, fp32-grade). Block = (b,win,head),
// 4 waves; wave owns 64 q-rows, iterates 8 k-chunks of 32 keys.
// S = QhKh+QhKl+QlKh (fp32 acc) -> P = exp(S/8) fp32 (scores bounded, no max)
// -> P split hi/lo through per-wave LDS (stride 40, 16B-aligned frag reads)
// -> O += PhVh+PhVl+PlVh.  l accumulated via cross-lane xor-reduce.
// Q frags live in registers whole kernel; K/V frags read from global (L2).
// ---------------------------------------------------------------------------
__global__ __launch_bounds__(256, 2)
void attn_mfma_kernel(const UST* __restrict__ Sp, UST* __restrict__ oh, UST* __restrict__ ol)
{
    __shared__ UST sPh[4 * 64 * 40];
    __shared__ UST sPl[4 * 64 * 40];
    const long SZ = 8388608L;
    const UST* Qh = Sp;
    const UST* Ql = Sp + SZ;
    const UST* Kh = Sp + 2 * SZ;
    const UST* Kl = Sp + 3 * SZ;
    const UST* Vth = Sp + 4 * SZ;
    const UST* Vtl = Sp + 5 * SZ;
    const int blk = blockIdx.x;
    const int h = blk & 15, w = (blk >> 4) & 15, b = blk >> 8;
    const long tok0 = (long)b * 4096 + w * 256;
    const int tid = threadIdx.x;
    const int lane = tid & 63;
    const int wv = tid >> 6;
    const int lm = lane & 15, lq = lane >> 4;

    // Q fragments (A-operand: m=lane&15, k=(lane>>4)*8+j), resident all kernel
    const long qrow0 = (long)h * 8192 + tok0 + wv * 64;
    s16x8 qhf[4][2], qlf[4][2];
#pragma unroll
    for (int mt = 0; mt < 4; mt++)
#pragma unroll
        for (int ks = 0; ks < 2; ks++) {
            const long o = (qrow0 + mt * 16 + lm) * 64 + ks * 32 + lq * 8;
            qhf[mt][ks] = *(const s16x8*)(Qh + o);
            qlf[mt][ks] = *(const s16x8*)(Ql + o);
        }
    const long krow0 = (long)h * 8192 + tok0;
    const long vbase = (long)blk * 16384;

    f32x4 Oacc[4][4] = {};
    float lsum[4][4] = {};
    UST* myPh = &sPh[wv * 2560];
    UST* myPl = &sPl[wv * 2560];

    for (int c = 0; c < 8; c++) {
        const int kt = c * 32;
        // ---- S = Q K^T (64q x 32k), split 3-product ----
        f32x4 S[4][2] = {};
#pragma unroll
        for (int nt = 0; nt < 2; nt++)
#pragma unroll
            for (int ks = 0; ks < 2; ks++) {
                const long o = (krow0 + kt + nt * 16 + lm) * 64 + ks * 32 + lq * 8;
                s16x8 khf = *(const s16x8*)(Kh + o);
                s16x8 klf = *(const s16x8*)(Kl + o);
#pragma unroll
                for (int mt = 0; mt < 4; mt++) {
                    S[mt][nt] = MFMA16(qhf[mt][ks], khf, S[mt][nt], 0, 0, 0);
                    S[mt][nt] = MFMA16(qhf[mt][ks], klf, S[mt][nt], 0, 0, 0);
                    S[mt][nt] = MFMA16(qlf[mt][ks], khf, S[mt][nt], 0, 0, 0);
                }
            }
        // ---- P = exp(S/8); l partial; write P split to LDS ----
#pragma unroll
        for (int mt = 0; mt < 4; mt++)
#pragma unroll
            for (int r = 0; r < 4; r++) {
                float p0 = __expf(S[mt][0][r] * 0.125f);
                float p1 = __expf(S[mt][1][r] * 0.125f);
                float part = p0 + p1;
                part += __shfl_xor(part, 1, 64);
                part += __shfl_xor(part, 2, 64);
                part += __shfl_xor(part, 4, 64);
                part += __shfl_xor(part, 8, 64);
                lsum[mt][r] += part;
                const int q = mt * 16 + lq * 4 + r;
                UST h0 = f2bf(p0), h1 = f2bf(p1);
                myPh[q * 40 + lm] = h0;
                myPh[q * 40 + 16 + lm] = h1;
                myPl[q * 40 + lm] = f2bf(p0 - bf2f(h0));
                myPl[q * 40 + 16 + lm] = f2bf(p1 - bf2f(h1));
            }
        // ---- O += P V (P from LDS A-frags, V^T from global B-frags) ----
#pragma unroll
        for (int mt = 0; mt < 4; mt++) {
            s16x8 phf = *(const s16x8*)(myPh + (mt * 16 + lm) * 40 + lq * 8);
            s16x8 plf = *(const s16x8*)(myPl + (mt * 16 + lm) * 40 + lq * 8);
#pragma unroll
            for (int dt = 0; dt < 4; dt++) {
                const long o = vbase + (dt * 16 + lm) * 256 + kt + lq * 8;
                s16x8 vhf = *(const s16x8*)(Vth + o);
                s16x8 vlf = *(const s16x8*)(Vtl + o);
                Oacc[mt][dt] = MFMA16(phf, vhf, Oacc[mt][dt], 0, 0, 0);
                Oacc[mt][dt] = MFMA16(phf, vlf, Oacc[mt][dt], 0, 0, 0);
                Oacc[mt][dt] = MFMA16(plf, vhf, Oacc[mt][dt], 0, 0, 0);
            }
        }
    }
    // ---- normalize + write split bf16 ----
#pragma unroll
    for (int mt = 0; mt < 4; mt++)
#pragma unroll
        for (int r = 0; r < 4; r++) {
            const float inv = 1.0f / lsum[mt][r];
            const long tok = tok0 + wv * 64 + mt * 16 + lq * 4 + r;
            UST* po = oh + tok * 1024 + h * 64;
            UST* plo = ol + tok * 1024 + h * 64;
#pragma unroll
            for (int dt = 0; dt < 4; dt++) {
                float f = Oacc[mt][dt][r] * inv;
                UST hv = f2bf(f);
                po[dt * 16 + lm] = hv;
                plo[dt * 16 + lm] = f2bf(f - bf2f(hv));
            }
        }
}

// ---------------------------------------------------------------------------
// Gate: logits (hi+lo fp32-grade), softmax, entropy, top-2 -> combine weights.
// ---------------------------------------------------------------------------
__global__ void gate_kernel(const UST* __restrict__ lnh, const UST* __restrict__ lnl,
                            const float* __restrict__ gw, const float* __restrict__ gb,
                            float* __restrict__ combine, float* __restrict__ ent_acc)
{
    const int tid = threadIdx.x;
    const int t = blockIdx.x * 4 + (tid >> 6);
    const int lane = tid & 63;
    const long row = (long)t + 2 + 4 * (t >> 12);
    const UST* ph = lnh + row * 1024;
    const UST* pl = lnl + row * 1024;
    float acc[8] = { 0, 0, 0, 0, 0, 0, 0, 0 };
    for (int c = 0; c < 16; c++) {
        int d = c * 64 + lane;
        float xv = bf2f(ph[d]) + bf2f(pl[d]);
        const float* wr = gw + (long)d * 8;
#pragma unroll
        for (int e = 0; e < 8; e++) acc[e] += xv * wr[e];
    }
#pragma unroll
    for (int e = 0; e < 8; e++)
        for (int o = 32; o > 0; o >>= 1) acc[e] += __shfl_xor(acc[e], o, 64);
    if (lane == 0) {
        float lg[8], p[8];
        float mx = -1e30f;
        for (int e = 0; e < 8; e++) { lg[e] = acc[e] + gb[e]; mx = fmaxf(mx, lg[e]); }
        float sum = 0;
        for (int e = 0; e < 8; e++) { p[e] = expf(lg[e] - mx); sum += p[e]; }
        float inv = 1.0f / sum;
        float ent = 0;
        for (int e = 0; e < 8; e++) { p[e] *= inv; ent -= p[e] * logf(p[e] + 1e-10f); }
        int i1 = 0; float v1 = -1e30f;
        for (int e = 0; e < 8; e++) if (p[e] > v1) { v1 = p[e]; i1 = e; }
        int i2 = 0; float v2 = -1e30f;
        for (int e = 0; e < 8; e++) if (e != i1 && p[e] > v2) { v2 = p[e]; i2 = e; }
        float inv2 = 1.0f / (v1 + v2);
        float cw[8] = { 0, 0, 0, 0, 0, 0, 0, 0 };
        cw[i1] = v1 * inv2; cw[i2] = v2 * inv2;
        float* co = combine + (long)t * 8;
        for (int e = 0; e < 8; e++) co[e] = cw[e];
        atomicAdd(ent_acc, ent);
    }
}

// out[t,f] += sum_j combine[t, half*4+j] * y[t, j*1024+f]
__global__ void moe_combine_kernel(const UST* __restrict__ y, const float* __restrict__ combine,
                                   float* __restrict__ out, int halfsel)
{
    const long gid = (long)blockIdx.x * 256 + threadIdx.x;
    const int t = (int)(gid >> 10), f = (int)(gid & 1023);
    const float* cw = combine + (long)t * 8 + halfsel * 4;
    const UST* yp = y + (long)t * 4096 + f;
    float s = cw[0] * bf2f(yp[0]) + cw[1] * bf2f(yp[1024])
            + cw[2] * bf2f(yp[2048]) + cw[3] * bf2f(yp[3072]);
    out[gid] += s;
}

__global__ void f32_to_bf16_kernel(const float* __restrict__ in, UST* __restrict__ out)
{
    long gid = ((long)blockIdx.x * 256 + threadIdx.x) * 4;
    float4 v = *(const float4*)(in + gid);
    out[gid] = f2bf(v.x); out[gid + 1] = f2bf(v.y);
    out[gid + 2] = f2bf(v.z); out[gid + 3] = f2bf(v.w);
}

__global__ void ent_final_kernel(const float* __restrict__ acc, float* __restrict__ out)
{
    out[0] = 0.1f * acc[0] * (1.0f / 8192.0f);
}

// ===========================================================================
extern "C" void kernel_launch(void* const* d_in, const int* in_sizes, int n_in,
                              void* d_out_, int out_size, void* d_ws, size_t ws_size,
                              hipStream_t stream)
{
    const float* x      = (const float*)d_in[0];
    const float* ln1_g  = (const float*)d_in[1];
    const float* ln1_b  = (const float*)d_in[2];
    const float* qkv_w  = (const float*)d_in[3];
    const float* qkv_b  = (const float*)d_in[4];
    const float* ao_w   = (const float*)d_in[5];
    const float* ao_b   = (const float*)d_in[6];
    const float* ln2_g  = (const float*)d_in[7];
    const float* ln2_b  = (const float*)d_in[8];
    const float* conv_w = (const float*)d_in[9];
    const float* conv_b = (const float*)d_in[10];
    const float* ln3_g  = (const float*)d_in[11];
    const float* ln3_b  = (const float*)d_in[12];
    const float* gate_w = (const float*)d_in[13];
    const float* gate_b = (const float*)d_in[14];
    const float* exp_w  = (const float*)d_in[15];
    const float* exp_b  = (const float*)d_in[16];
    const float* ff_w1  = (const float*)d_in[17];
    const float* ff_b1  = (const float*)d_in[18];
    const float* ff_w2  = (const float*)d_in[19];
    const float* ff_b2  = (const float*)d_in[20];
    float* out = (float*)d_out_;

    char* ws = (char*)d_ws;
    size_t off = 0;
    auto alloc = [&](size_t bytes) -> char* {
        char* p = ws + off;
        off += (bytes + 255) & ~(size_t)255;
        return p;
    };
    UST* qkvWh = (UST*)alloc(3072 * 1024 * 2);
    UST* qkvWl = (UST*)alloc(3072 * 1024 * 2);
    UST* aoWh  = (UST*)alloc(1024 * 1024 * 2);
    UST* aoWl  = (UST*)alloc(1024 * 1024 * 2);
    UST* convCh = (UST*)alloc(1024L * 3072 * 2);   // [n=1024][k=3072] concat taps
    UST* convCl = (UST*)alloc(1024L * 3072 * 2);
    UST* expW  = (UST*)alloc(8192L * 1024 * 2);
    UST* ff1W  = (UST*)alloc(4096L * 1024 * 2);
    UST* ff2W  = (UST*)alloc(4096L * 1024 * 2);
    const size_t LN_BYTES = 8200L * 1024 * 2;
    UST* LNh = (UST*)alloc(LN_BYTES);
    UST* LNl = (UST*)alloc(LN_BYTES);
    float* combine = (float*)alloc(8192 * 8 * 4);
    float* entacc  = (float*)alloc(256);
    char*  BIG = alloc(8192L * 3072 * 4);     // Sp (6x16MB) during attn; y/h1 later
    UST* OH = (UST*)alloc(8192L * 1024 * 2);  // attn out hi; later x3 bf16
    UST* OL = (UST*)alloc(8192L * 1024 * 2);
    if (off > ws_size) return;  // ws too small -> deliberate clean fail

    UST* Sp   = (UST*)BIG;      // [Qh|Ql|Kh|Kl|Vth|Vtl]
    UST* ybuf = (UST*)BIG;
    UST* h1   = (UST*)BIG;
    UST* x3h  = OH;

    // ---- weight prep (every call; ws is re-poisoned) ----
    auto nb = [](long n) { return (unsigned)((n + 255) / 256); };
    prep_t_kernel<<<dim3(48, 32), 256, 0, stream>>>(qkv_w, qkvWh, qkvWl, 3072, 1024);
    prep_t_kernel<<<dim3(16, 32), 256, 0, stream>>>(ao_w, aoWh, aoWl, 1024, 1024);
    for (int k = 0; k < 3; k++)
        prep_w_kernel<<<nb(1024L * 1024), 256, 0, stream>>>(conv_w + k, convCh, convCl,
                                                            1024, 3, 3072, 3072, k * 1024, 1024L * 1024);
    for (int e = 0; e < 8; e++)
        prep_t_kernel<<<dim3(16, 32), 256, 0, stream>>>(exp_w + (long)e * 1048576, expW + (long)e * 1048576,
                                                        nullptr, 1024, 1024);
    prep_t_kernel<<<dim3(64, 32), 256, 0, stream>>>(ff_w1, ff1W, nullptr, 4096, 1024);
    prep_t_kernel<<<dim3(16, 128), 256, 0, stream>>>(ff_w2, ff2W, nullptr, 1024, 4096);

    ln_pad_kernel<<<8, 256, 0, stream>>>(LNh, LNl);
    hipMemsetAsync(entacc, 0, 4, stream);

    // ---- attention block ----
    ln_split_kernel<<<8192, 256, 0, stream>>>(x, ln1_g, ln1_b, LNh, LNl);
    gemm_bt_kernel<2, true, 0><<<dim3(24, 32), 512, 0, stream>>>(LNh, LNl, qkvWh, qkvWl, qkv_b, nullptr,
                                                                 nullptr, nullptr, Sp, 8192, 3072, 1024, 1024, 2, 4);
    attn_mfma_kernel<<<512, 256, 0, stream>>>(Sp, OH, OL);
    gemm_bt_kernel<0, true, 0><<<dim3(8, 32), 512, 0, stream>>>(OH, OL, aoWh, aoWl, ao_b, x,
                                                                out, nullptr, nullptr, 8192, 1024, 1024, 1024, 0, 0);
    // ---- dilated conv block: ONE fused GEMM, K=3072 (3 shifted segments) ----
    ln_split_kernel<<<8192, 256, 0, stream>>>(out, ln2_g, ln2_b, LNh, LNl);
    gemm_bt_kernel<0, true, 1024><<<dim3(8, 32), 512, 0, stream>>>(LNh, LNl, convCh, convCl, conv_b, out,
                                                                   out, nullptr, nullptr, 8192, 1024, 3072, 1024, 0, 4);
    // ---- MoE ----
    ln_split_kernel<<<8192, 256, 0, stream>>>(out, ln3_g, ln3_b, LNh, LNl);
    gate_kernel<<<2048, 256, 0, stream>>>(LNh, LNl, gate_w, gate_b, combine, entacc);
    ent_final_kernel<<<1, 1, 0, stream>>>(entacc, out + 8388608);
    for (int hh = 0; hh < 2; hh++) {
        gemm_bt_kernel<1, false, 0><<<dim3(32, 32), 512, 0, stream>>>(LNh, nullptr, expW + (long)hh * 4096 * 1024,
                                                                      nullptr, exp_b + hh * 4096, nullptr,
                                                                      nullptr, ybuf, nullptr, 8192, 4096, 1024, 1024, 2, 4);
        moe_combine_kernel<<<32768, 256, 0, stream>>>(ybuf, combine, out, hh);
    }
    // ---- FFN ----
    f32_to_bf16_kernel<<<8192, 256, 0, stream>>>(out, x3h);
    gemm_bt_kernel<1, false, 0><<<dim3(32, 32), 512, 0, stream>>>(x3h, nullptr, ff1W, nullptr, ff_b1, nullptr,
                                                                  nullptr, h1, nullptr, 8192, 4096, 1024, 1024, 0, 0);
    gemm_bt_kernel<0, false, 0><<<dim3(8, 32), 512, 0, stream>>>(h1, nullptr, ff2W, nullptr, ff_b2, out,
                                                                 out, nullptr, nullptr, 8192, 1024, 4096, 4096, 0, 0);
}

// Round 4
// 1409.788 us; speedup vs baseline: 1.1527x; 1.0780x over previous
//
#include <hip/hip_runtime.h>
#include <hip/hip_bf16.h>
#include <math.h>

// ============================================================================
// ImprovedTransformerBlock on MI355X.  R7: revert GEMM to the R5 base (128x128,
// 4 waves, 2 blocks/CU, counted-vmcnt double-buffer; R5's LDS swizzle removed —
// measured null, wave frag reads are structurally conflict-free).  Two changes:
// (a) MFMA dependency-chain break: split products issued as three separate
//     i/j sweeps (hh, then hl, then lh) -> 16 independent MFMAs between
//     successive touches of each accumulator (was back-to-back {hl;lh} on the
//     same acc).  Per-element accumulation order unchanged -> bit-identical.
// (b) XCD-aware bijective block swizzle (T1): wg=(orig%8)*(nwg/8)+orig/8,
//     all GEMM grids are %8==0 -> panel-sharing blocks land on one XCD L2.
// Precision plan: pre-gate path bf16x2-split MFMA (fp32-grade, protects top-2
// routing); post-gate (experts, FFN) plain bf16 MFMA.
// ============================================================================

typedef unsigned short UST;
typedef unsigned int uint32;
typedef float f32x4 __attribute__((ext_vector_type(4)));
using s16x8 = __attribute__((ext_vector_type(8))) short;   // 8 bf16 = 4 VGPRs

#define DEV __device__ __forceinline__
#define MFMA16 __builtin_amdgcn_mfma_f32_16x16x32_bf16

// async global->LDS, 16 bytes/lane; lds dst is wave-uniform base + lane*16
#define GLL(g, l) __builtin_amdgcn_global_load_lds( \
    (const __attribute__((address_space(1))) unsigned int*)(g), \
    (__attribute__((address_space(3))) unsigned int*)(l), 16, 0, 0)

// raw sync primitives (counted vmcnt pipeline) — asm with memory clobber so
// compiler-generated ds_read/GLL cannot migrate across them.
#define BARRIER()  asm volatile("s_barrier" ::: "memory")
#define LGKM0()    asm volatile("s_waitcnt lgkmcnt(0)" ::: "memory")
#define VM0()      asm volatile("s_waitcnt vmcnt(0)" ::: "memory")

DEV UST f2bf(float f) {                       // round-to-nearest-even fp32->bf16
    uint32 u = __float_as_uint(f);
    u += 0x7FFFu + ((u >> 16) & 1u);
    return (UST)(u >> 16);
}
DEV float bf2f(UST h) { return __uint_as_float(((uint32)h) << 16); }
DEV float gelu_f(float x) { return 0.5f * x * (1.0f + erff(x * 0.7071067811865475f)); }

// ---------------------------------------------------------------------------
// LayerNorm -> split bf16 (hi/lo), conv-padded row layout: row(t)=t+2+4*(t>>12)
// ---------------------------------------------------------------------------
__global__ void ln_split_kernel(const float* __restrict__ x,
                                const float* __restrict__ g, const float* __restrict__ b,
                                UST* __restrict__ oh, UST* __restrict__ ol)
{
    const int t = blockIdx.x;
    const int tid = threadIdx.x;
    const float4 v = ((const float4*)(x + (long)t * 1024))[tid];
    float s = v.x + v.y + v.z + v.w;
    float q = v.x * v.x + v.y * v.y + v.z * v.z + v.w * v.w;
    for (int o = 32; o > 0; o >>= 1) { s += __shfl_xor(s, o, 64); q += __shfl_xor(q, o, 64); }
    __shared__ float ss[4], sq[4];
    const int wave = tid >> 6, lane = tid & 63;
    if (lane == 0) { ss[wave] = s; sq[wave] = q; }
    __syncthreads();
    s = ss[0] + ss[1] + ss[2] + ss[3];
    q = sq[0] + sq[1] + sq[2] + sq[3];
    const float mean = s * (1.0f / 1024.0f);
    const float var = q * (1.0f / 1024.0f) - mean * mean;
    const float rstd = 1.0f / sqrtf(var + 1e-5f);
    const long row = (long)t + 2 + 4 * (t >> 12);
    UST* ph = oh + row * 1024 + tid * 4;
    UST* pl = ol + row * 1024 + tid * 4;
    const float4 gg = ((const float4*)g)[tid];
    const float4 bb = ((const float4*)b)[tid];
    float vv[4] = { v.x, v.y, v.z, v.w };
    float gv[4] = { gg.x, gg.y, gg.z, gg.w };
    float bv[4] = { bb.x, bb.y, bb.z, bb.w };
#pragma unroll
    for (int j = 0; j < 4; j++) {
        float f = (vv[j] - mean) * rstd * gv[j] + bv[j];
        UST hi = f2bf(f);
        ph[j] = hi;
        pl[j] = f2bf(f - bf2f(hi));
    }
}

// zero the conv-pad rows {b*4100 + 0,1,4098,4099} of LNh/LNl
__global__ void ln_pad_kernel(UST* __restrict__ oh, UST* __restrict__ ol)
{
    const int blk = blockIdx.x;          // 8 blocks
    const int b = blk >> 2, rsel = blk & 3;
    const long row = (long)b * 4100 + (rsel < 2 ? rsel : 4096 + rsel);
    const int tid = threadIdx.x;
    *(ushort4*)(oh + row * 1024 + tid * 4) = make_ushort4(0, 0, 0, 0);
    *(ushort4*)(ol + row * 1024 + tid * 4) = make_ushort4(0, 0, 0, 0);
}

// ---------------------------------------------------------------------------
// Coalesced transpose prep: dst[n*K+k] = src[k*N+n], bf16 hi (+lo).
// ---------------------------------------------------------------------------
__global__ void prep_t_kernel(const float* __restrict__ src, UST* __restrict__ dh,
                              UST* __restrict__ dl, int N, int K)
{
    __shared__ float tile[32][65];
    const int k0 = blockIdx.y * 32, n0 = blockIdx.x * 64;
    const int t = threadIdx.x;
    const int nn = t & 63, kk = t >> 6;
#pragma unroll
    for (int i = 0; i < 8; i++)
        tile[kk + i * 4][nn] = src[(long)(k0 + kk + i * 4) * N + n0 + nn];
    __syncthreads();
    const int kw = (t & 7) * 4;
#pragma unroll
    for (int pass = 0; pass < 2; pass++) {
        const int nw = (t >> 3) + pass * 32;
        UST hv[4], lv[4];
#pragma unroll
        for (int j = 0; j < 4; j++) {
            float v = tile[kw + j][nw];
            hv[j] = f2bf(v);
            lv[j] = f2bf(v - bf2f(hv[j]));
        }
        UST* bh = dh + (long)(n0 + nw) * K + k0 + kw;
        *(ushort4*)bh = make_ushort4(hv[0], hv[1], hv[2], hv[3]);
        if (dl) {
            UST* bl = dl + (long)(n0 + nw) * K + k0 + kw;
            *(ushort4*)bl = make_ushort4(lv[0], lv[1], lv[2], lv[3]);
        }
    }
}

// conv taps into concatenated B: dst[n*dstK + dstOff + k] = src[k*sr + n*sc]
__global__ void prep_w_kernel(const float* __restrict__ src, UST* __restrict__ dh,
                              UST* __restrict__ dl, int K, long sr, long sc,
                              int dstK, int dstOff, long total)
{
    long gid = (long)blockIdx.x * 256 + threadIdx.x;
    if (gid >= total) return;
    long n = gid / K, k = gid - n * K;
    float v = src[k * sr + n * sc];
    UST hi = f2bf(v);
    long di = n * dstK + dstOff + k;
    dh[di] = hi;
    if (dl) dl[di] = f2bf(v - bf2f(hi));
}

// ---------------------------------------------------------------------------
// GEMM: C[M,N] = A[M,K] * B^T[N,K]  (bf16, fp32 accum, MFMA 16x16x32)
// 128x128 tile, BK=32, 256 threads, global_load_lds(16B) staging.
// R7 = R5 pipeline minus swizzle, plus chain-broken MFMA and XCD block swizzle.
// Pipeline per 32-K tile (2x unrolled, compile-time LDS bases):
//   s_waitcnt vmcnt(8|4)   own cur-tile GLLs landed (next tile stays in flight)
//   s_barrier              everyone's cur-tile landed
//   ds_read all frags      cur tile -> regs
//   lgkmcnt(0); s_barrier  all waves' reads done -> cur buf reusable (WAR)
//   stage(t+2 -> cur buf)  GLL issue overlaps MFMA
//   setprio(1) MFMA sweeps (hh | hl | lh — chain-broken) setprio(0)
// Tail peels the last two tiles with vmcnt(8|4) then vmcnt(0).
// SPLIT: A=Ah+Al, B=Bh+Bl -> AhBh + AhBl + AlBh (fp32-grade); per-element
// accumulation order hh,hl,lh — identical to R4/R5/R6.
// A row stride KA; A k-offset = k0 + (k0>>10)*ASHIFT (conv seg trick: segment
// s reads +2048 elements = +2 rows -> tap s hits row t+2s).
// EPI 0: Cf = acc(+bias)(+resid) fp32. EPI 1: Cb = bf16(gelu(acc+bias)).
// EPI 2: scatter split bf16 into Sp = [Qh|Ql|Kh|Kl|Vth|Vtl] (attention prep).
// ---------------------------------------------------------------------------
template<int EPI, bool SPLIT, int ASHIFT>
__global__ __launch_bounds__(256)
void gemm_bt_kernel(const UST* __restrict__ Ah, const UST* __restrict__ Al,
                    const UST* __restrict__ Bh, const UST* __restrict__ Bl,
                    const float* __restrict__ bias, const float* __restrict__ resid,
                    float* __restrict__ Cf, UST* __restrict__ Cb, UST* __restrict__ Sp,
                    int M, int N, int K, int KA, int rb, int radd)
{
    constexpr int ABUF = (SPLIT ? 2 : 1) * 4096;   // USTs per k-tile buffer
    __shared__ UST sA[2 * ABUF];
    __shared__ UST sB[2 * ABUF];
    const int tid = threadIdx.x;
    const int lane = tid & 63;
    const int wv = __builtin_amdgcn_readfirstlane(tid >> 6);
    const int wr = wv >> 1, wc = wv & 1;
    const int lm = lane & 15, lq = lane >> 4;

    // XCD-aware bijective block swizzle (all GEMM grids have nwg % 8 == 0):
    // consecutive remapped blocks share operand panels within one XCD's L2.
    const unsigned nwg = gridDim.x * gridDim.y;
    const unsigned orig = blockIdx.y * gridDim.x + blockIdx.x;
    const unsigned wg = (orig & 7u) * (nwg >> 3) + (orig >> 3);
    const int bx = (int)(wg % gridDim.x), by = (int)(wg / gridDim.x);
    const long m0 = (long)by * 128, n0 = (long)bx * 128;

    const int lr = lane >> 2, lc = (lane & 3) * 8;
    const int rA0 = wv * 32 + lr, rA1 = wv * 32 + 16 + lr;
    const long mtop = m0 >> 12;              // tiles never straddle 4096 rows
    const UST* gA0 = Ah + (m0 + rA0 + rb + (long)radd * mtop) * KA + lc;
    const UST* gA1 = Ah + (m0 + rA1 + rb + (long)radd * mtop) * KA + lc;
    const UST* gB0 = Bh + (n0 + rA0) * K + lc;
    const UST* gB1 = Bh + (n0 + rA1) * K + lc;
    const UST* gA0l = SPLIT ? (Al + (m0 + rA0 + rb + (long)radd * mtop) * KA + lc) : nullptr;
    const UST* gA1l = SPLIT ? (Al + (m0 + rA1 + rb + (long)radd * mtop) * KA + lc) : nullptr;
    const UST* gB0l = SPLIT ? (Bl + (n0 + rA0) * K + lc) : nullptr;
    const UST* gB1l = SPLIT ? (Bl + (n0 + rA1) * K + lc) : nullptr;

    f32x4 acc[4][4] = {};
    s16x8 ah[4], bh[4], al[4], bl[4];

    // stage k-tile kk into buffer with per-wave bases dA/dB (wave-uniform)
    auto stage = [&](int kk, UST* dA, UST* dB) {
        const long aoff = ASHIFT ? (long)kk + (long)(kk >> 10) * ASHIFT : (long)kk;
        GLL(gA0 + aoff, dA); GLL(gA1 + aoff, dA + 512);
        GLL(gB0 + kk, dB); GLL(gB1 + kk, dB + 512);
        if (SPLIT) {
            GLL(gA0l + aoff, dA + 4096); GLL(gA1l + aoff, dA + 512 + 4096);
            GLL(gB0l + kk, dB + 4096); GLL(gB1l + kk, dB + 512 + 4096);
        }
    };
    // load all fragments of the staged tile at LDS bases cA/cB
    auto loads = [&](const UST* cA, const UST* cB) {
#pragma unroll
        for (int i = 0; i < 4; i++) {
            ah[i] = *(const s16x8*)&cA[(wr * 64 + i * 16 + lm) * 32 + lq * 8];
            bh[i] = *(const s16x8*)&cB[(wc * 64 + i * 16 + lm) * 32 + lq * 8];
        }
        if constexpr (SPLIT) {
#pragma unroll
            for (int i = 0; i < 4; i++) {
                al[i] = *(const s16x8*)&cA[4096 + (wr * 64 + i * 16 + lm) * 32 + lq * 8];
                bl[i] = *(const s16x8*)&cB[4096 + (wc * 64 + i * 16 + lm) * 32 + lq * 8];
            }
        }
    };
    // chain-broken MFMA cluster: three independent sweeps; each acc register
    // is touched once per sweep (16 issues apart) — no back-to-back dep chains.
    auto mfma_all = [&]() {
        __builtin_amdgcn_s_setprio(1);
#pragma unroll
        for (int i = 0; i < 4; i++)
#pragma unroll
            for (int j = 0; j < 4; j++)
                acc[i][j] = MFMA16(ah[i], bh[j], acc[i][j], 0, 0, 0);
        if constexpr (SPLIT) {
#pragma unroll
            for (int i = 0; i < 4; i++)
#pragma unroll
                for (int j = 0; j < 4; j++)
                    acc[i][j] = MFMA16(ah[i], bl[j], acc[i][j], 0, 0, 0);
#pragma unroll
            for (int i = 0; i < 4; i++)
#pragma unroll
                for (int j = 0; j < 4; j++)
                    acc[i][j] = MFMA16(al[i], bh[j], acc[i][j], 0, 0, 0);
        }
        __builtin_amdgcn_s_setprio(0);
    };
    auto vm_cur = [&]() {
        if constexpr (SPLIT) asm volatile("s_waitcnt vmcnt(8)" ::: "memory");
        else                 asm volatile("s_waitcnt vmcnt(4)" ::: "memory");
    };

    UST* wA0 = &sA[wv * 1024];               // wave-uniform LDS bases
    UST* wB0 = &sB[wv * 1024];
    UST* wA1 = &sA[ABUF + wv * 1024];
    UST* wB1 = &sB[ABUF + wv * 1024];

    stage(0, wA0, wB0);                      // tile 0 -> buf0
    stage(32, wA1, wB1);                     // tile 1 -> buf1
    for (int k0 = 0; k0 + 64 < K; k0 += 64) {
        vm_cur(); BARRIER();                 // tile k0/32 (buf0) fully in LDS
        loads(&sA[0], &sB[0]);
        LGKM0(); BARRIER();                  // all waves done reading buf0
        stage(k0 + 64, wA0, wB0);            // overlap with MFMA below
        mfma_all();
        vm_cur(); BARRIER();                 // tile k0/32+1 (buf1) in LDS
        loads(&sA[ABUF], &sB[ABUF]);
        LGKM0(); BARRIER();
        stage(k0 + 96, wA1, wB1);
        mfma_all();
    }
    // tail: tiles T-2 (buf0) and T-1 (buf1), no more staging
    vm_cur(); BARRIER();
    loads(&sA[0], &sB[0]);
    mfma_all();
    VM0(); BARRIER();
    loads(&sA[ABUF], &sB[ABUF]);
    mfma_all();

    // C/D layout (m89/m91-verified): col = lane&15, row = (lane>>4)*4 + reg
    const long SZ = 8388608L;
    const int colbase = (int)n0 + wc * 64;          // wave-uniform
    const int part = colbase >> 10;                 // EPI2: 0=Q,1=K,2=V
    const int hh = (colbase & 1023) >> 6;
    UST* H = (EPI == 2) ? (Sp + (long)part * 2 * SZ) : nullptr;
    UST* Lo = (EPI == 2) ? (H + SZ) : nullptr;
#pragma unroll
    for (int i = 0; i < 4; i++) {
#pragma unroll
        for (int j = 0; j < 4; j++) {
#pragma unroll
            for (int r = 0; r < 4; r++) {
                const long grow = m0 + wr * 64 + i * 16 + lq * 4 + r;
                const long gcol = n0 + wc * 64 + j * 16 + lm;
                float v = acc[i][j][r];
                if (bias) v += bias[gcol];
                if (EPI == 0) {
                    const long idx = grow * N + gcol;
                    if (resid) v += resid[idx];
                    Cf[idx] = v;
                } else if (EPI == 1) {
                    Cb[grow * N + gcol] = f2bf(gelu_f(v));
                } else {
                    const int d = j * 16 + lm;      // col within head
                    long idx;
                    if (part < 2) {
                        idx = ((long)hh * 8192 + grow) * 64 + d;
                    } else {
                        const int bb = (int)(grow >> 12), ww = (int)((grow >> 8) & 15),
                                  tt = (int)(grow & 255);
                        idx = ((long)((bb * 16 + ww) * 16 + hh)) * 16384 + (long)d * 256 + tt;
                    }
                    UST hi = f2bf(v);
                    H[idx] = hi;
                    Lo[idx] = f2bf(v - bf2f(hi));
                }
            }
        }
    }
}

// ---------------------------------------------------------------------------
// MFMA windowed attention (split-bf16, fp32-grade). Block = (b,win,head),
// 4 waves; wave owns 64 q-rows, iterates 8 k-chunks of 32 keys.
// S = QhKh+QhKl+QlKh (fp32 acc) -> P = exp(S/8) fp32 (scores bounded, no max)
// -> P split hi/lo through per-wave LDS (stride 40, 16B-aligned frag reads)
// -> O += PhVh+PhVl+PlVh.  l accumulated via cross-lane xor-reduce.
// Q frags live in registers whole kernel; K/V frags read from global (L2).
// ---------------------------------------------------------------------------
__global__ __launch_bounds__(256, 2)
void attn_mfma_kernel(const UST* __restrict__ Sp, UST* __restrict__ oh, UST* __restrict__ ol)
{
    __shared__ UST sPh[4 * 64 * 40];
    __shared__ UST sPl[4 * 64 * 40];
    const long SZ = 8388608L;
    const UST* Qh = Sp;
    const UST* Ql = Sp + SZ;
    const UST* Kh = Sp + 2 * SZ;
    const UST* Kl = Sp + 3 * SZ;
    const UST* Vth = Sp + 4 * SZ;
    const UST* Vtl = Sp + 5 * SZ;
    const int blk = blockIdx.x;
    const int h = blk & 15, w = (blk >> 4) & 15, b = blk >> 8;
    const long tok0 = (long)b * 4096 + w * 256;
    const int tid = threadIdx.x;
    const int lane = tid & 63;
    const int wv = tid >> 6;
    const int lm = lane & 15, lq = lane >> 4;

    // Q fragments (A-operand: m=lane&15, k=(lane>>4)*8+j), resident all kernel
    const long qrow0 = (long)h * 8192 + tok0 + wv * 64;
    s16x8 qhf[4][2], qlf[4][2];
#pragma unroll
    for (int mt = 0; mt < 4; mt++)
#pragma unroll
        for (int ks = 0; ks < 2; ks++) {
            const long o = (qrow0 + mt * 16 + lm) * 64 + ks * 32 + lq * 8;
            qhf[mt][ks] = *(const s16x8*)(Qh + o);
            qlf[mt][ks] = *(const s16x8*)(Ql + o);
        }
    const long krow0 = (long)h * 8192 + tok0;
    const long vbase = (long)blk * 16384;

    f32x4 Oacc[4][4] = {};
    float lsum[4][4] = {};
    UST* myPh = &sPh[wv * 2560];
    UST* myPl = &sPl[wv * 2560];

    for (int c = 0; c < 8; c++) {
        const int kt = c * 32;
        // ---- S = Q K^T (64q x 32k), split 3-product ----
        f32x4 S[4][2] = {};
#pragma unroll
        for (int nt = 0; nt < 2; nt++)
#pragma unroll
            for (int ks = 0; ks < 2; ks++) {
                const long o = (krow0 + kt + nt * 16 + lm) * 64 + ks * 32 + lq * 8;
                s16x8 khf = *(const s16x8*)(Kh + o);
                s16x8 klf = *(const s16x8*)(Kl + o);
#pragma unroll
                for (int mt = 0; mt < 4; mt++) {
                    S[mt][nt] = MFMA16(qhf[mt][ks], khf, S[mt][nt], 0, 0, 0);
                    S[mt][nt] = MFMA16(qhf[mt][ks], klf, S[mt][nt], 0, 0, 0);
                    S[mt][nt] = MFMA16(qlf[mt][ks], khf, S[mt][nt], 0, 0, 0);
                }
            }
        // ---- P = exp(S/8); l partial; write P split to LDS ----
#pragma unroll
        for (int mt = 0; mt < 4; mt++)
#pragma unroll
            for (int r = 0; r < 4; r++) {
                float p0 = __expf(S[mt][0][r] * 0.125f);
                float p1 = __expf(S[mt][1][r] * 0.125f);
                float part = p0 + p1;
                part += __shfl_xor(part, 1, 64);
                part += __shfl_xor(part, 2, 64);
                part += __shfl_xor(part, 4, 64);
                part += __shfl_xor(part, 8, 64);
                lsum[mt][r] += part;
                const int q = mt * 16 + lq * 4 + r;
                UST h0 = f2bf(p0), h1 = f2bf(p1);
                myPh[q * 40 + lm] = h0;
                myPh[q * 40 + 16 + lm] = h1;
                myPl[q * 40 + lm] = f2bf(p0 - bf2f(h0));
                myPl[q * 40 + 16 + lm] = f2bf(p1 - bf2f(h1));
            }
        // ---- O += P V (P from LDS A-frags, V^T from global B-frags) ----
#pragma unroll
        for (int mt = 0; mt < 4; mt++) {
            s16x8 phf = *(const s16x8*)(myPh + (mt * 16 + lm) * 40 + lq * 8);
            s16x8 plf = *(const s16x8*)(myPl + (mt * 16 + lm) * 40 + lq * 8);
#pragma unroll
            for (int dt = 0; dt < 4; dt++) {
                const long o = vbase + (dt * 16 + lm) * 256 + kt + lq * 8;
                s16x8 vhf = *(const s16x8*)(Vth + o);
                s16x8 vlf = *(const s16x8*)(Vtl + o);
                Oacc[mt][dt] = MFMA16(phf, vhf, Oacc[mt][dt], 0, 0, 0);
                Oacc[mt][dt] = MFMA16(phf, vlf, Oacc[mt][dt], 0, 0, 0);
                Oacc[mt][dt] = MFMA16(plf, vhf, Oacc[mt][dt], 0, 0, 0);
            }
        }
    }
    // ---- normalize + write split bf16 ----
#pragma unroll
    for (int mt = 0; mt < 4; mt++)
#pragma unroll
        for (int r = 0; r < 4; r++) {
            const float inv = 1.0f / lsum[mt][r];
            const long tok = tok0 + wv * 64 + mt * 16 + lq * 4 + r;
            UST* po = oh + tok * 1024 + h * 64;
            UST* plo = ol + tok * 1024 + h * 64;
#pragma unroll
            for (int dt = 0; dt < 4; dt++) {
                float f = Oacc[mt][dt][r] * inv;
                UST hv = f2bf(f);
                po[dt * 16 + lm] = hv;
                plo[dt * 16 + lm] = f2bf(f - bf2f(hv));
            }
        }
}

// ---------------------------------------------------------------------------
// Gate: logits (hi+lo fp32-grade), softmax, entropy, top-2 -> combine weights.
// ---------------------------------------------------------------------------
__global__ void gate_kernel(const UST* __restrict__ lnh, const UST* __restrict__ lnl,
                            const float* __restrict__ gw, const float* __restrict__ gb,
                            float* __restrict__ combine, float* __restrict__ ent_acc)
{
    const int tid = threadIdx.x;
    const int t = blockIdx.x * 4 + (tid >> 6);
    const int lane = tid & 63;
    const long row = (long)t + 2 + 4 * (t >> 12);
    const UST* ph = lnh + row * 1024;
    const UST* pl = lnl + row * 1024;
    float acc[8] = { 0, 0, 0, 0, 0, 0, 0, 0 };
    for (int c = 0; c < 16; c++) {
        int d = c * 64 + lane;
        float xv = bf2f(ph[d]) + bf2f(pl[d]);
        const float* wr = gw + (long)d * 8;
#pragma unroll
        for (int e = 0; e < 8; e++) acc[e] += xv * wr[e];
    }
#pragma unroll
    for (int e = 0; e < 8; e++)
        for (int o = 32; o > 0; o >>= 1) acc[e] += __shfl_xor(acc[e], o, 64);
    if (lane == 0) {
        float lg[8], p[8];
        float mx = -1e30f;
        for (int e = 0; e < 8; e++) { lg[e] = acc[e] + gb[e]; mx = fmaxf(mx, lg[e]); }
        float sum = 0;
        for (int e = 0; e < 8; e++) { p[e] = expf(lg[e] - mx); sum += p[e]; }
        float inv = 1.0f / sum;
        float ent = 0;
        for (int e = 0; e < 8; e++) { p[e] *= inv; ent -= p[e] * logf(p[e] + 1e-10f); }
        int i1 = 0; float v1 = -1e30f;
        for (int e = 0; e < 8; e++) if (p[e] > v1) { v1 = p[e]; i1 = e; }
        int i2 = 0; float v2 = -1e30f;
        for (int e = 0; e < 8; e++) if (e != i1 && p[e] > v2) { v2 = p[e]; i2 = e; }
        float inv2 = 1.0f / (v1 + v2);
        float cw[8] = { 0, 0, 0, 0, 0, 0, 0, 0 };
        cw[i1] = v1 * inv2; cw[i2] = v2 * inv2;
        float* co = combine + (long)t * 8;
        for (int e = 0; e < 8; e++) co[e] = cw[e];
        atomicAdd(ent_acc, ent);
    }
}

// out[t,f] += sum_j combine[t, half*4+j] * y[t, j*1024+f]
__global__ void moe_combine_kernel(const UST* __restrict__ y, const float* __restrict__ combine,
                                   float* __restrict__ out, int halfsel)
{
    const long gid = (long)blockIdx.x * 256 + threadIdx.x;
    const int t = (int)(gid >> 10), f = (int)(gid & 1023);
    const float* cw = combine + (long)t * 8 + halfsel * 4;
    const UST* yp = y + (long)t * 4096 + f;
    float s = cw[0] * bf2f(yp[0]) + cw[1] * bf2f(yp[1024])
            + cw[2] * bf2f(yp[2048]) + cw[3] * bf2f(yp[3072]);
    out[gid] += s;
}

__global__ void f32_to_bf16_kernel(const float* __restrict__ in, UST* __restrict__ out)
{
    long gid = ((long)blockIdx.x * 256 + threadIdx.x) * 4;
    float4 v = *(const float4*)(in + gid);
    out[gid] = f2bf(v.x); out[gid + 1] = f2bf(v.y);
    out[gid + 2] = f2bf(v.z); out[gid + 3] = f2bf(v.w);
}

__global__ void ent_final_kernel(const float* __restrict__ acc, float* __restrict__ out)
{
    out[0] = 0.1f * acc[0] * (1.0f / 8192.0f);
}

// ===========================================================================
extern "C" void kernel_launch(void* const* d_in, const int* in_sizes, int n_in,
                              void* d_out_, int out_size, void* d_ws, size_t ws_size,
                              hipStream_t stream)
{
    const float* x      = (const float*)d_in[0];
    const float* ln1_g  = (const float*)d_in[1];
    const float* ln1_b  = (const float*)d_in[2];
    const float* qkv_w  = (const float*)d_in[3];
    const float* qkv_b  = (const float*)d_in[4];
    const float* ao_w   = (const float*)d_in[5];
    const float* ao_b   = (const float*)d_in[6];
    const float* ln2_g  = (const float*)d_in[7];
    const float* ln2_b  = (const float*)d_in[8];
    const float* conv_w = (const float*)d_in[9];
    const float* conv_b = (const float*)d_in[10];
    const float* ln3_g  = (const float*)d_in[11];
    const float* ln3_b  = (const float*)d_in[12];
    const float* gate_w = (const float*)d_in[13];
    const float* gate_b = (const float*)d_in[14];
    const float* exp_w  = (const float*)d_in[15];
    const float* exp_b  = (const float*)d_in[16];
    const float* ff_w1  = (const float*)d_in[17];
    const float* ff_b1  = (const float*)d_in[18];
    const float* ff_w2  = (const float*)d_in[19];
    const float* ff_b2  = (const float*)d_in[20];
    float* out = (float*)d_out_;

    char* ws = (char*)d_ws;
    size_t off = 0;
    auto alloc = [&](size_t bytes) -> char* {
        char* p = ws + off;
        off += (bytes + 255) & ~(size_t)255;
        return p;
    };
    UST* qkvWh = (UST*)alloc(3072 * 1024 * 2);
    UST* qkvWl = (UST*)alloc(3072 * 1024 * 2);
    UST* aoWh  = (UST*)alloc(1024 * 1024 * 2);
    UST* aoWl  = (UST*)alloc(1024 * 1024 * 2);
    UST* convCh = (UST*)alloc(1024L * 3072 * 2);   // [n=1024][k=3072] concat taps
    UST* convCl = (UST*)alloc(1024L * 3072 * 2);
    UST* expW  = (UST*)alloc(8192L * 1024 * 2);
    UST* ff1W  = (UST*)alloc(4096L * 1024 * 2);
    UST* ff2W  = (UST*)alloc(4096L * 1024 * 2);
    const size_t LN_BYTES = 8200L * 1024 * 2;
    UST* LNh = (UST*)alloc(LN_BYTES);
    UST* LNl = (UST*)alloc(LN_BYTES);
    float* combine = (float*)alloc(8192 * 8 * 4);
    float* entacc  = (float*)alloc(256);
    char*  BIG = alloc(8192L * 3072 * 4);     // Sp (6x16MB) during attn; y/h1 later
    UST* OH = (UST*)alloc(8192L * 1024 * 2);  // attn out hi; later x3 bf16
    UST* OL = (UST*)alloc(8192L * 1024 * 2);
    if (off > ws_size) return;  // ws too small -> deliberate clean fail

    UST* Sp   = (UST*)BIG;      // [Qh|Ql|Kh|Kl|Vth|Vtl]
    UST* ybuf = (UST*)BIG;
    UST* h1   = (UST*)BIG;
    UST* x3h  = OH;

    // ---- weight prep (every call; ws is re-poisoned) ----
    auto nb = [](long n) { return (unsigned)((n + 255) / 256); };
    prep_t_kernel<<<dim3(48, 32), 256, 0, stream>>>(qkv_w, qkvWh, qkvWl, 3072, 1024);
    prep_t_kernel<<<dim3(16, 32), 256, 0, stream>>>(ao_w, aoWh, aoWl, 1024, 1024);
    for (int k = 0; k < 3; k++)
        prep_w_kernel<<<nb(1024L * 1024), 256, 0, stream>>>(conv_w + k, convCh, convCl,
                                                            1024, 3, 3072, 3072, k * 1024, 1024L * 1024);
    for (int e = 0; e < 8; e++)
        prep_t_kernel<<<dim3(16, 32), 256, 0, stream>>>(exp_w + (long)e * 1048576, expW + (long)e * 1048576,
                                                        nullptr, 1024, 1024);
    prep_t_kernel<<<dim3(64, 32), 256, 0, stream>>>(ff_w1, ff1W, nullptr, 4096, 1024);
    prep_t_kernel<<<dim3(16, 128), 256, 0, stream>>>(ff_w2, ff2W, nullptr, 1024, 4096);

    ln_pad_kernel<<<8, 256, 0, stream>>>(LNh, LNl);
    hipMemsetAsync(entacc, 0, 4, stream);

    // ---- attention block ----
    ln_split_kernel<<<8192, 256, 0, stream>>>(x, ln1_g, ln1_b, LNh, LNl);
    gemm_bt_kernel<2, true, 0><<<dim3(24, 64), 256, 0, stream>>>(LNh, LNl, qkvWh, qkvWl, qkv_b, nullptr,
                                                                 nullptr, nullptr, Sp, 8192, 3072, 1024, 1024, 2, 4);
    attn_mfma_kernel<<<512, 256, 0, stream>>>(Sp, OH, OL);
    gemm_bt_kernel<0, true, 0><<<dim3(8, 64), 256, 0, stream>>>(OH, OL, aoWh, aoWl, ao_b, x,
                                                                out, nullptr, nullptr, 8192, 1024, 1024, 1024, 0, 0);
    // ---- dilated conv block: ONE fused GEMM, K=3072 (3 shifted segments) ----
    ln_split_kernel<<<8192, 256, 0, stream>>>(out, ln2_g, ln2_b, LNh, LNl);
    gemm_bt_kernel<0, true, 1024><<<dim3(8, 64), 256, 0, stream>>>(LNh, LNl, convCh, convCl, conv_b, out,
                                                                   out, nullptr, nullptr, 8192, 1024, 3072, 1024, 0, 4);
    // ---- MoE ----
    ln_split_kernel<<<8192, 256, 0, stream>>>(out, ln3_g, ln3_b, LNh, LNl);
    gate_kernel<<<2048, 256, 0, stream>>>(LNh, LNl, gate_w, gate_b, combine, entacc);
    ent_final_kernel<<<1, 1, 0, stream>>>(entacc, out + 8388608);
    for (int hh = 0; hh < 2; hh++) {
        gemm_bt_kernel<1, false, 0><<<dim3(32, 64), 256, 0, stream>>>(LNh, nullptr, expW + (long)hh * 4096 * 1024,
                                                                      nullptr, exp_b + hh * 4096, nullptr,
                                                                      nullptr, ybuf, nullptr, 8192, 4096, 1024, 1024, 2, 4);
        moe_combine_kernel<<<32768, 256, 0, stream>>>(ybuf, combine, out, hh);
    }
    // ---- FFN ----
    f32_to_bf16_kernel<<<8192, 256, 0, stream>>>(out, x3h);
    gemm_bt_kernel<1, false, 0><<<dim3(32, 64), 256, 0, stream>>>(x3h, nullptr, ff1W, nullptr, ff_b1, nullptr,
                                                                  nullptr, h1, nullptr, 8192, 4096, 1024, 1024, 0, 0);
    gemm_bt_kernel<0, false, 0><<<dim3(8, 64), 256, 0, stream>>>(h1, nullptr, ff2W, nullptr, ff_b2, out,
                                                                 out, nullptr, nullptr, 8192, 1024, 4096, 4096, 0, 0);
}

// Round 5
// 1358.874 us; speedup vs baseline: 1.1959x; 1.0375x over previous
//
#include <hip/hip_runtime.h>
#include <hip/hip_bf16.h>
#include <math.h>

// ============================================================================
// ImprovedTransformerBlock on MI355X.  R8 = R7 (chain-broken MFMA + XCD
// swizzle, counted-vmcnt dbuf 128x128 GEMM) + SPARSE MoE: experts are computed
// only for their routed tokens (top-2), exact w.r.t. the reference since
// combine weights are exactly zero off the top-2.
//   gate_kernel  -> also builds per-expert token lists (cnt8 + perm of padded
//                   row indices, 8 x 8192 segments)
//   gemm_bt_kernel<GATHER=true> -> gathered-A GEMM over token-expert pairs
//                   (16384 pairs = 34.4 GF vs 137 GF dense), tile->(e,mtile)
//                   mapped on-device from cnt8, early-exit spare blocks,
//                   epilogue: atomicAdd(out, gelu(acc+bias_e)*combine) in fp32
// Removed: 2x dense expert GEMMs, 2x moe_combine, ybuf traffic.
// Precision: pre-gate path bf16x2-split MFMA (fp32-grade); post-gate plain
// bf16 MFMA; expert epilogue now fp32 end-to-end (one bf16 rounding removed).
// ============================================================================

typedef unsigned short UST;
typedef unsigned int uint32;
typedef float f32x4 __attribute__((ext_vector_type(4)));
using s16x8 = __attribute__((ext_vector_type(8))) short;   // 8 bf16 = 4 VGPRs

#define DEV __device__ __forceinline__
#define MFMA16 __builtin_amdgcn_mfma_f32_16x16x32_bf16

// async global->LDS, 16 bytes/lane; lds dst is wave-uniform base + lane*16
#define GLL(g, l) __builtin_amdgcn_global_load_lds( \
    (const __attribute__((address_space(1))) unsigned int*)(g), \
    (__attribute__((address_space(3))) unsigned int*)(l), 16, 0, 0)

// raw sync primitives (counted vmcnt pipeline) — asm with memory clobber so
// compiler-generated ds_read/GLL cannot migrate across them.
#define BARRIER()  asm volatile("s_barrier" ::: "memory")
#define LGKM0()    asm volatile("s_waitcnt lgkmcnt(0)" ::: "memory")
#define VM0()      asm volatile("s_waitcnt vmcnt(0)" ::: "memory")

DEV UST f2bf(float f) {                       // round-to-nearest-even fp32->bf16
    uint32 u = __float_as_uint(f);
    u += 0x7FFFu + ((u >> 16) & 1u);
    return (UST)(u >> 16);
}
DEV float bf2f(UST h) { return __uint_as_float(((uint32)h) << 16); }
DEV float gelu_f(float x) { return 0.5f * x * (1.0f + erff(x * 0.7071067811865475f)); }

// ---------------------------------------------------------------------------
// LayerNorm -> split bf16 (hi/lo), conv-padded row layout: row(t)=t+2+4*(t>>12)
// ---------------------------------------------------------------------------
__global__ void ln_split_kernel(const float* __restrict__ x,
                                const float* __restrict__ g, const float* __restrict__ b,
                                UST* __restrict__ oh, UST* __restrict__ ol)
{
    const int t = blockIdx.x;
    const int tid = threadIdx.x;
    const float4 v = ((const float4*)(x + (long)t * 1024))[tid];
    float s = v.x + v.y + v.z + v.w;
    float q = v.x * v.x + v.y * v.y + v.z * v.z + v.w * v.w;
    for (int o = 32; o > 0; o >>= 1) { s += __shfl_xor(s, o, 64); q += __shfl_xor(q, o, 64); }
    __shared__ float ss[4], sq[4];
    const int wave = tid >> 6, lane = tid & 63;
    if (lane == 0) { ss[wave] = s; sq[wave] = q; }
    __syncthreads();
    s = ss[0] + ss[1] + ss[2] + ss[3];
    q = sq[0] + sq[1] + sq[2] + sq[3];
    const float mean = s * (1.0f / 1024.0f);
    const float var = q * (1.0f / 1024.0f) - mean * mean;
    const float rstd = 1.0f / sqrtf(var + 1e-5f);
    const long row = (long)t + 2 + 4 * (t >> 12);
    UST* ph = oh + row * 1024 + tid * 4;
    UST* pl = ol + row * 1024 + tid * 4;
    const float4 gg = ((const float4*)g)[tid];
    const float4 bb = ((const float4*)b)[tid];
    float vv[4] = { v.x, v.y, v.z, v.w };
    float gv[4] = { gg.x, gg.y, gg.z, gg.w };
    float bv[4] = { bb.x, bb.y, bb.z, bb.w };
#pragma unroll
    for (int j = 0; j < 4; j++) {
        float f = (vv[j] - mean) * rstd * gv[j] + bv[j];
        UST hi = f2bf(f);
        ph[j] = hi;
        pl[j] = f2bf(f - bf2f(hi));
    }
}

// zero the conv-pad rows {b*4100 + 0,1,4098,4099} of LNh/LNl
__global__ void ln_pad_kernel(UST* __restrict__ oh, UST* __restrict__ ol)
{
    const int blk = blockIdx.x;          // 8 blocks
    const int b = blk >> 2, rsel = blk & 3;
    const long row = (long)b * 4100 + (rsel < 2 ? rsel : 4096 + rsel);
    const int tid = threadIdx.x;
    *(ushort4*)(oh + row * 1024 + tid * 4) = make_ushort4(0, 0, 0, 0);
    *(ushort4*)(ol + row * 1024 + tid * 4) = make_ushort4(0, 0, 0, 0);
}

// ---------------------------------------------------------------------------
// Coalesced transpose prep: dst[n*K+k] = src[k*N+n], bf16 hi (+lo).
// ---------------------------------------------------------------------------
__global__ void prep_t_kernel(const float* __restrict__ src, UST* __restrict__ dh,
                              UST* __restrict__ dl, int N, int K)
{
    __shared__ float tile[32][65];
    const int k0 = blockIdx.y * 32, n0 = blockIdx.x * 64;
    const int t = threadIdx.x;
    const int nn = t & 63, kk = t >> 6;
#pragma unroll
    for (int i = 0; i < 8; i++)
        tile[kk + i * 4][nn] = src[(long)(k0 + kk + i * 4) * N + n0 + nn];
    __syncthreads();
    const int kw = (t & 7) * 4;
#pragma unroll
    for (int pass = 0; pass < 2; pass++) {
        const int nw = (t >> 3) + pass * 32;
        UST hv[4], lv[4];
#pragma unroll
        for (int j = 0; j < 4; j++) {
            float v = tile[kw + j][nw];
            hv[j] = f2bf(v);
            lv[j] = f2bf(v - bf2f(hv[j]));
        }
        UST* bh = dh + (long)(n0 + nw) * K + k0 + kw;
        *(ushort4*)bh = make_ushort4(hv[0], hv[1], hv[2], hv[3]);
        if (dl) {
            UST* bl = dl + (long)(n0 + nw) * K + k0 + kw;
            *(ushort4*)bl = make_ushort4(lv[0], lv[1], lv[2], lv[3]);
        }
    }
}

// conv taps into concatenated B: dst[n*dstK + dstOff + k] = src[k*sr + n*sc]
__global__ void prep_w_kernel(const float* __restrict__ src, UST* __restrict__ dh,
                              UST* __restrict__ dl, int K, long sr, long sc,
                              int dstK, int dstOff, long total)
{
    long gid = (long)blockIdx.x * 256 + threadIdx.x;
    if (gid >= total) return;
    long n = gid / K, k = gid - n * K;
    float v = src[k * sr + n * sc];
    UST hi = f2bf(v);
    long di = n * dstK + dstOff + k;
    dh[di] = hi;
    if (dl) dl[di] = f2bf(v - bf2f(hi));
}

// ---------------------------------------------------------------------------
// GEMM: C[M,N] = A[M,K] * B^T[N,K]  (bf16, fp32 accum, MFMA 16x16x32)
// 128x128 tile, BK=32, 256 threads, global_load_lds(16B) staging.
// Counted-vmcnt double-buffer pipeline (R5), chain-broken MFMA sweeps (R7),
// XCD-aware bijective block swizzle (R7, non-gather only).
// GATHER mode (R8): blockIdx.y = linear M-tile over expert segments; the
// (expert, mtile) pair is derived on-device from cnt8; A rows come through
// perm (conv-padded row indices into Ah=LNh); B/bias offset by expert id;
// EPI 3 epilogue: atomicAdd(Cf[token], gelu(acc+bias_e)*combine[token][e]).
// SPLIT: A=Ah+Al, B=Bh+Bl -> AhBh + AhBl + AlBh (fp32-grade).
// A row stride KA; A k-offset = k0 + (k0>>10)*ASHIFT (conv seg trick).
// EPI 0: Cf = acc(+bias)(+resid) fp32. EPI 1: Cb = bf16(gelu(acc+bias)).
// EPI 2: scatter split bf16 into Sp = [Qh|Ql|Kh|Kl|Vth|Vtl] (attention prep).
// EPI 3: gathered MoE epilogue (GATHER only).
// ---------------------------------------------------------------------------
template<int EPI, bool SPLIT, int ASHIFT, bool GATHER>
__global__ __launch_bounds__(256)
void gemm_bt_kernel(const UST* __restrict__ Ah, const UST* __restrict__ Al,
                    const UST* __restrict__ Bh, const UST* __restrict__ Bl,
                    const float* __restrict__ bias, const float* __restrict__ resid,
                    float* __restrict__ Cf, UST* __restrict__ Cb, UST* __restrict__ Sp,
                    int M, int N, int K, int KA, int rb, int radd,
                    const int* __restrict__ cnt8, const int* __restrict__ perm,
                    const float* __restrict__ combine)
{
    constexpr int ABUF = (SPLIT ? 2 : 1) * 4096;   // USTs per k-tile buffer
    __shared__ UST sA[2 * ABUF];
    __shared__ UST sB[2 * ABUF];
    const int tid = threadIdx.x;
    const int lane = tid & 63;
    const int wv = __builtin_amdgcn_readfirstlane(tid >> 6);
    const int wr = wv >> 1, wc = wv & 1;
    const int lm = lane & 15, lq = lane >> 4;

    int eidx = 0, cnt_e = 0, segbase = 0;
    long m0, n0;
    if constexpr (GATHER) {
        int mt = (int)blockIdx.y;
        int cnts[8];
#pragma unroll
        for (int e2 = 0; e2 < 8; e2++) cnts[e2] = cnt8[e2];
        int e2 = 0;
        for (;;) {
            const int te = (cnts[e2] + 127) >> 7;
            if (mt < te) break;
            mt -= te;
            if (++e2 == 8) return;           // spare block, uniform exit
        }
        eidx = e2; cnt_e = cnts[e2]; segbase = e2 << 13;
        m0 = (long)mt * 128;                 // segment-local row base
        n0 = (long)blockIdx.x * 128;
    } else {
        // XCD-aware bijective block swizzle (all GEMM grids have nwg % 8 == 0)
        const unsigned nwg = gridDim.x * gridDim.y;
        const unsigned orig = blockIdx.y * gridDim.x + blockIdx.x;
        const unsigned wg = (orig & 7u) * (nwg >> 3) + (orig >> 3);
        m0 = (long)(wg / gridDim.x) * 128;
        n0 = (long)(wg % gridDim.x) * 128;
    }

    const int lr = lane >> 2, lc = (lane & 3) * 8;
    const int rA0 = wv * 32 + lr, rA1 = wv * 32 + 16 + lr;
    const UST *gA0, *gA1;
    const UST *gA0l = nullptr, *gA1l = nullptr, *gB0l = nullptr, *gB1l = nullptr;
    const UST* Bhe = Bh;
    if constexpr (GATHER) {
        const int p0 = (int)m0 + rA0, p1 = (int)m0 + rA1;
        const int i0 = (p0 < cnt_e) ? perm[segbase + p0] : 0;  // row 0 = zero pad
        const int i1 = (p1 < cnt_e) ? perm[segbase + p1] : 0;
        gA0 = Ah + (long)i0 * KA + lc;
        gA1 = Ah + (long)i1 * KA + lc;
        Bhe = Bh + ((long)eidx << 20);       // expert weight block [1024x1024]
    } else {
        const long mtop = m0 >> 12;          // tiles never straddle 4096 rows
        gA0 = Ah + (m0 + rA0 + rb + (long)radd * mtop) * KA + lc;
        gA1 = Ah + (m0 + rA1 + rb + (long)radd * mtop) * KA + lc;
        if constexpr (SPLIT) {
            gA0l = Al + (m0 + rA0 + rb + (long)radd * mtop) * KA + lc;
            gA1l = Al + (m0 + rA1 + rb + (long)radd * mtop) * KA + lc;
        }
    }
    const UST* gB0 = Bhe + (n0 + rA0) * K + lc;
    const UST* gB1 = Bhe + (n0 + rA1) * K + lc;
    if constexpr (SPLIT) {
        gB0l = Bl + (n0 + rA0) * K + lc;
        gB1l = Bl + (n0 + rA1) * K + lc;
    }

    f32x4 acc[4][4] = {};
    s16x8 ah[4], bh[4], al[4], bl[4];

    // stage k-tile kk into buffer with per-wave bases dA/dB (wave-uniform)
    auto stage = [&](int kk, UST* dA, UST* dB) {
        const long aoff = ASHIFT ? (long)kk + (long)(kk >> 10) * ASHIFT : (long)kk;
        GLL(gA0 + aoff, dA); GLL(gA1 + aoff, dA + 512);
        GLL(gB0 + kk, dB); GLL(gB1 + kk, dB + 512);
        if (SPLIT) {
            GLL(gA0l + aoff, dA + 4096); GLL(gA1l + aoff, dA + 512 + 4096);
            GLL(gB0l + kk, dB + 4096); GLL(gB1l + kk, dB + 512 + 4096);
        }
    };
    // load all fragments of the staged tile at LDS bases cA/cB
    auto loads = [&](const UST* cA, const UST* cB) {
#pragma unroll
        for (int i = 0; i < 4; i++) {
            ah[i] = *(const s16x8*)&cA[(wr * 64 + i * 16 + lm) * 32 + lq * 8];
            bh[i] = *(const s16x8*)&cB[(wc * 64 + i * 16 + lm) * 32 + lq * 8];
        }
        if constexpr (SPLIT) {
#pragma unroll
            for (int i = 0; i < 4; i++) {
                al[i] = *(const s16x8*)&cA[4096 + (wr * 64 + i * 16 + lm) * 32 + lq * 8];
                bl[i] = *(const s16x8*)&cB[4096 + (wc * 64 + i * 16 + lm) * 32 + lq * 8];
            }
        }
    };
    // chain-broken MFMA cluster: three independent sweeps; each acc register
    // is touched once per sweep (16 issues apart) — no back-to-back dep chains.
    auto mfma_all = [&]() {
        __builtin_amdgcn_s_setprio(1);
#pragma unroll
        for (int i = 0; i < 4; i++)
#pragma unroll
            for (int j = 0; j < 4; j++)
                acc[i][j] = MFMA16(ah[i], bh[j], acc[i][j], 0, 0, 0);
        if constexpr (SPLIT) {
#pragma unroll
            for (int i = 0; i < 4; i++)
#pragma unroll
                for (int j = 0; j < 4; j++)
                    acc[i][j] = MFMA16(ah[i], bl[j], acc[i][j], 0, 0, 0);
#pragma unroll
            for (int i = 0; i < 4; i++)
#pragma unroll
                for (int j = 0; j < 4; j++)
                    acc[i][j] = MFMA16(al[i], bh[j], acc[i][j], 0, 0, 0);
        }
        __builtin_amdgcn_s_setprio(0);
    };
    auto vm_cur = [&]() {
        if constexpr (SPLIT) asm volatile("s_waitcnt vmcnt(8)" ::: "memory");
        else                 asm volatile("s_waitcnt vmcnt(4)" ::: "memory");
    };

    UST* wA0 = &sA[wv * 1024];               // wave-uniform LDS bases
    UST* wB0 = &sB[wv * 1024];
    UST* wA1 = &sA[ABUF + wv * 1024];
    UST* wB1 = &sB[ABUF + wv * 1024];

    stage(0, wA0, wB0);                      // tile 0 -> buf0
    stage(32, wA1, wB1);                     // tile 1 -> buf1
    for (int k0 = 0; k0 + 64 < K; k0 += 64) {
        vm_cur(); BARRIER();                 // tile k0/32 (buf0) fully in LDS
        loads(&sA[0], &sB[0]);
        LGKM0(); BARRIER();                  // all waves done reading buf0
        stage(k0 + 64, wA0, wB0);            // overlap with MFMA below
        mfma_all();
        vm_cur(); BARRIER();                 // tile k0/32+1 (buf1) in LDS
        loads(&sA[ABUF], &sB[ABUF]);
        LGKM0(); BARRIER();
        stage(k0 + 96, wA1, wB1);
        mfma_all();
    }
    // tail: tiles T-2 (buf0) and T-1 (buf1), no more staging
    vm_cur(); BARRIER();
    loads(&sA[0], &sB[0]);
    mfma_all();
    VM0(); BARRIER();
    loads(&sA[ABUF], &sB[ABUF]);
    mfma_all();

    // C/D layout (m89/m91-verified): col = lane&15, row = (lane>>4)*4 + reg
    const long SZ = 8388608L;
    const int colbase = (int)n0 + wc * 64;          // wave-uniform
    const int part = colbase >> 10;                 // EPI2: 0=Q,1=K,2=V
    const int hh = (colbase & 1023) >> 6;
    UST* H = (EPI == 2) ? (Sp + (long)part * 2 * SZ) : nullptr;
    UST* Lo = (EPI == 2) ? (H + SZ) : nullptr;
    const float* bias_e = bias;
    if constexpr (GATHER) bias_e = bias + (eidx << 10);
#pragma unroll
    for (int i = 0; i < 4; i++) {
#pragma unroll
        for (int j = 0; j < 4; j++) {
#pragma unroll
            for (int r = 0; r < 4; r++) {
                const long grow = m0 + wr * 64 + i * 16 + lq * 4 + r;
                const long gcol = n0 + wc * 64 + j * 16 + lm;
                float v = acc[i][j][r];
                if (bias) v += bias_e[gcol];
                if (EPI == 0) {
                    const long idx = grow * N + gcol;
                    if (resid) v += resid[idx];
                    Cf[idx] = v;
                } else if (EPI == 1) {
                    Cb[grow * N + gcol] = f2bf(gelu_f(v));
                } else if (EPI == 3) {
                    if (grow < cnt_e) {                 // grow is segment-local
                        const int prow = perm[segbase + grow];
                        const int tok = prow - ((prow < 4100) ? 2 : 6);
                        const float wgt = combine[(long)tok * 8 + eidx];
                        atomicAdd(&Cf[(long)tok * 1024 + gcol], gelu_f(v) * wgt);
                    }
                } else {
                    const int d = j * 16 + lm;      // col within head
                    long idx;
                    if (part < 2) {
                        idx = ((long)hh * 8192 + grow) * 64 + d;
                    } else {
                        const int bb = (int)(grow >> 12), ww = (int)((grow >> 8) & 15),
                                  tt = (int)(grow & 255);
                        idx = ((long)((bb * 16 + ww) * 16 + hh)) * 16384 + (long)d * 256 + tt;
                    }
                    UST hi = f2bf(v);
                    H[idx] = hi;
                    Lo[idx] = f2bf(v - bf2f(hi));
                }
            }
        }
    }
}

// ---------------------------------------------------------------------------
// MFMA windowed attention (split-bf16, fp32-grade). Block = (b,win,head),
// 4 waves; wave owns 64 q-rows, iterates 8 k-chunks of 32 keys.
// S = QhKh+QhKl+QlKh (fp32 acc) -> P = exp(S/8) fp32 (scores bounded, no max)
// -> P split hi/lo through per-wave LDS (stride 40, 16B-aligned frag reads)
// -> O += PhVh+PhVl+PlVh.  l accumulated via cross-lane xor-reduce.
// Q frags live in registers whole kernel; K/V frags read from global (L2).
// ---------------------------------------------------------------------------
__global__ __launch_bounds__(256, 2)
void attn_mfma_kernel(const UST* __restrict__ Sp, UST* __restrict__ oh, UST* __restrict__ ol)
{
    __shared__ UST sPh[4 * 64 * 40];
    __shared__ UST sPl[4 * 64 * 40];
    const long SZ = 8388608L;
    const UST* Qh = Sp;
    const UST* Ql = Sp + SZ;
    const UST* Kh = Sp + 2 * SZ;
    const UST* Kl = Sp + 3 * SZ;
    const UST* Vth = Sp + 4 * SZ;
    const UST* Vtl = Sp + 5 * SZ;
    const int blk = blockIdx.x;
    const int h = blk & 15, w = (blk >> 4) & 15, b = blk >> 8;
    const long tok0 = (long)b * 4096 + w * 256;
    const int tid = threadIdx.x;
    const int lane = tid & 63;
    const int wv = tid >> 6;
    const int lm = lane & 15, lq = lane >> 4;

    // Q fragments (A-operand: m=lane&15, k=(lane>>4)*8+j), resident all kernel
    const long qrow0 = (long)h * 8192 + tok0 + wv * 64;
    s16x8 qhf[4][2], qlf[4][2];
#pragma unroll
    for (int mt = 0; mt < 4; mt++)
#pragma unroll
        for (int ks = 0; ks < 2; ks++) {
            const long o = (qrow0 + mt * 16 + lm) * 64 + ks * 32 + lq * 8;
            qhf[mt][ks] = *(const s16x8*)(Qh + o);
            qlf[mt][ks] = *(const s16x8*)(Ql + o);
        }
    const long krow0 = (long)h * 8192 + tok0;
    const long vbase = (long)blk * 16384;

    f32x4 Oacc[4][4] = {};
    float lsum[4][4] = {};
    UST* myPh = &sPh[wv * 2560];
    UST* myPl = &sPl[wv * 2560];

    for (int c = 0; c < 8; c++) {
        const int kt = c * 32;
        // ---- S = Q K^T (64q x 32k), split 3-product ----
        f32x4 S[4][2] = {};
#pragma unroll
        for (int nt = 0; nt < 2; nt++)
#pragma unroll
            for (int ks = 0; ks < 2; ks++) {
                const long o = (krow0 + kt + nt * 16 + lm) * 64 + ks * 32 + lq * 8;
                s16x8 khf = *(const s16x8*)(Kh + o);
                s16x8 klf = *(const s16x8*)(Kl + o);
#pragma unroll
                for (int mt = 0; mt < 4; mt++) {
                    S[mt][nt] = MFMA16(qhf[mt][ks], khf, S[mt][nt], 0, 0, 0);
                    S[mt][nt] = MFMA16(qhf[mt][ks], klf, S[mt][nt], 0, 0, 0);
                    S[mt][nt] = MFMA16(qlf[mt][ks], khf, S[mt][nt], 0, 0, 0);
                }
            }
        // ---- P = exp(S/8); l partial; write P split to LDS ----
#pragma unroll
        for (int mt = 0; mt < 4; mt++)
#pragma unroll
            for (int r = 0; r < 4; r++) {
                float p0 = __expf(S[mt][0][r] * 0.125f);
                float p1 = __expf(S[mt][1][r] * 0.125f);
                float part = p0 + p1;
                part += __shfl_xor(part, 1, 64);
                part += __shfl_xor(part, 2, 64);
                part += __shfl_xor(part, 4, 64);
                part += __shfl_xor(part, 8, 64);
                lsum[mt][r] += part;
                const int q = mt * 16 + lq * 4 + r;
                UST h0 = f2bf(p0), h1 = f2bf(p1);
                myPh[q * 40 + lm] = h0;
                myPh[q * 40 + 16 + lm] = h1;
                myPl[q * 40 + lm] = f2bf(p0 - bf2f(h0));
                myPl[q * 40 + 16 + lm] = f2bf(p1 - bf2f(h1));
            }
        // ---- O += P V (P from LDS A-frags, V^T from global B-frags) ----
#pragma unroll
        for (int mt = 0; mt < 4; mt++) {
            s16x8 phf = *(const s16x8*)(myPh + (mt * 16 + lm) * 40 + lq * 8);
            s16x8 plf = *(const s16x8*)(myPl + (mt * 16 + lm) * 40 + lq * 8);
#pragma unroll
            for (int dt = 0; dt < 4; dt++) {
                const long o = vbase + (dt * 16 + lm) * 256 + kt + lq * 8;
                s16x8 vhf = *(const s16x8*)(Vth + o);
                s16x8 vlf = *(const s16x8*)(Vtl + o);
                Oacc[mt][dt] = MFMA16(phf, vhf, Oacc[mt][dt], 0, 0, 0);
                Oacc[mt][dt] = MFMA16(phf, vlf, Oacc[mt][dt], 0, 0, 0);
                Oacc[mt][dt] = MFMA16(plf, vhf, Oacc[mt][dt], 0, 0, 0);
            }
        }
    }
    // ---- normalize + write split bf16 ----
#pragma unroll
    for (int mt = 0; mt < 4; mt++)
#pragma unroll
        for (int r = 0; r < 4; r++) {
            const float inv = 1.0f / lsum[mt][r];
            const long tok = tok0 + wv * 64 + mt * 16 + lq * 4 + r;
            UST* po = oh + tok * 1024 + h * 64;
            UST* plo = ol + tok * 1024 + h * 64;
#pragma unroll
            for (int dt = 0; dt < 4; dt++) {
                float f = Oacc[mt][dt][r] * inv;
                UST hv = f2bf(f);
                po[dt * 16 + lm] = hv;
                plo[dt * 16 + lm] = f2bf(f - bf2f(hv));
            }
        }
}

// ---------------------------------------------------------------------------
// Gate: logits (hi+lo fp32-grade), softmax, entropy, top-2 -> combine weights
// + per-expert token lists (cnt8 histogram, perm of padded row indices).
// ---------------------------------------------------------------------------
__global__ void gate_kernel(const UST* __restrict__ lnh, const UST* __restrict__ lnl,
                            const float* __restrict__ gw, const float* __restrict__ gb,
                            float* __restrict__ combine, float* __restrict__ ent_acc,
                            int* __restrict__ cnt8, int* __restrict__ perm)
{
    const int tid = threadIdx.x;
    const int t = blockIdx.x * 4 + (tid >> 6);
    const int lane = tid & 63;
    const long row = (long)t + 2 + 4 * (t >> 12);
    const UST* ph = lnh + row * 1024;
    const UST* pl = lnl + row * 1024;
    float acc[8] = { 0, 0, 0, 0, 0, 0, 0, 0 };
    for (int c = 0; c < 16; c++) {
        int d = c * 64 + lane;
        float xv = bf2f(ph[d]) + bf2f(pl[d]);
        const float* wr = gw + (long)d * 8;
#pragma unroll
        for (int e = 0; e < 8; e++) acc[e] += xv * wr[e];
    }
#pragma unroll
    for (int e = 0; e < 8; e++)
        for (int o = 32; o > 0; o >>= 1) acc[e] += __shfl_xor(acc[e], o, 64);
    if (lane == 0) {
        float lg[8], p[8];
        float mx = -1e30f;
        for (int e = 0; e < 8; e++) { lg[e] = acc[e] + gb[e]; mx = fmaxf(mx, lg[e]); }
        float sum = 0;
        for (int e = 0; e < 8; e++) { p[e] = expf(lg[e] - mx); sum += p[e]; }
        float inv = 1.0f / sum;
        float ent = 0;
        for (int e = 0; e < 8; e++) { p[e] *= inv; ent -= p[e] * logf(p[e] + 1e-10f); }
        int i1 = 0; float v1 = -1e30f;
        for (int e = 0; e < 8; e++) if (p[e] > v1) { v1 = p[e]; i1 = e; }
        int i2 = 0; float v2 = -1e30f;
        for (int e = 0; e < 8; e++) if (e != i1 && p[e] > v2) { v2 = p[e]; i2 = e; }
        float inv2 = 1.0f / (v1 + v2);
        float cw[8] = { 0, 0, 0, 0, 0, 0, 0, 0 };
        cw[i1] = v1 * inv2; cw[i2] = v2 * inv2;
        float* co = combine + (long)t * 8;
        for (int e = 0; e < 8; e++) co[e] = cw[e];
        const int s1 = atomicAdd(&cnt8[i1], 1);
        perm[(i1 << 13) + s1] = (int)row;
        const int s2 = atomicAdd(&cnt8[i2], 1);
        perm[(i2 << 13) + s2] = (int)row;
        atomicAdd(ent_acc, ent);
    }
}

__global__ void f32_to_bf16_kernel(const float* __restrict__ in, UST* __restrict__ out)
{
    long gid = ((long)blockIdx.x * 256 + threadIdx.x) * 4;
    float4 v = *(const float4*)(in + gid);
    out[gid] = f2bf(v.x); out[gid + 1] = f2bf(v.y);
    out[gid + 2] = f2bf(v.z); out[gid + 3] = f2bf(v.w);
}

__global__ void ent_final_kernel(const float* __restrict__ acc, float* __restrict__ out)
{
    out[0] = 0.1f * acc[0] * (1.0f / 8192.0f);
}

// ===========================================================================
extern "C" void kernel_launch(void* const* d_in, const int* in_sizes, int n_in,
                              void* d_out_, int out_size, void* d_ws, size_t ws_size,
                              hipStream_t stream)
{
    const float* x      = (const float*)d_in[0];
    const float* ln1_g  = (const float*)d_in[1];
    const float* ln1_b  = (const float*)d_in[2];
    const float* qkv_w  = (const float*)d_in[3];
    const float* qkv_b  = (const float*)d_in[4];
    const float* ao_w   = (const float*)d_in[5];
    const float* ao_b   = (const float*)d_in[6];
    const float* ln2_g  = (const float*)d_in[7];
    const float* ln2_b  = (const float*)d_in[8];
    const float* conv_w = (const float*)d_in[9];
    const float* conv_b = (const float*)d_in[10];
    const float* ln3_g  = (const float*)d_in[11];
    const float* ln3_b  = (const float*)d_in[12];
    const float* gate_w = (const float*)d_in[13];
    const float* gate_b = (const float*)d_in[14];
    const float* exp_w  = (const float*)d_in[15];
    const float* exp_b  = (const float*)d_in[16];
    const float* ff_w1  = (const float*)d_in[17];
    const float* ff_b1  = (const float*)d_in[18];
    const float* ff_w2  = (const float*)d_in[19];
    const float* ff_b2  = (const float*)d_in[20];
    float* out = (float*)d_out_;

    char* ws = (char*)d_ws;
    size_t off = 0;
    auto alloc = [&](size_t bytes) -> char* {
        char* p = ws + off;
        off += (bytes + 255) & ~(size_t)255;
        return p;
    };
    UST* qkvWh = (UST*)alloc(3072 * 1024 * 2);
    UST* qkvWl = (UST*)alloc(3072 * 1024 * 2);
    UST* aoWh  = (UST*)alloc(1024 * 1024 * 2);
    UST* aoWl  = (UST*)alloc(1024 * 1024 * 2);
    UST* convCh = (UST*)alloc(1024L * 3072 * 2);   // [n=1024][k=3072] concat taps
    UST* convCl = (UST*)alloc(1024L * 3072 * 2);
    UST* expW  = (UST*)alloc(8192L * 1024 * 2);
    UST* ff1W  = (UST*)alloc(4096L * 1024 * 2);
    UST* ff2W  = (UST*)alloc(4096L * 1024 * 2);
    const size_t LN_BYTES = 8200L * 1024 * 2;
    UST* LNh = (UST*)alloc(LN_BYTES);
    UST* LNl = (UST*)alloc(LN_BYTES);
    float* combine = (float*)alloc(8192 * 8 * 4);
    float* entacc  = (float*)alloc(256);
    int*   cnt8    = (int*)alloc(256);
    int*   perm    = (int*)alloc(8 * 8192 * 4);
    char*  BIG = alloc(8192L * 3072 * 4);     // Sp (6x16MB) during attn; h1 later
    UST* OH = (UST*)alloc(8192L * 1024 * 2);  // attn out hi; later x3 bf16
    UST* OL = (UST*)alloc(8192L * 1024 * 2);
    if (off > ws_size) return;  // ws too small -> deliberate clean fail

    UST* Sp   = (UST*)BIG;      // [Qh|Ql|Kh|Kl|Vth|Vtl]
    UST* h1   = (UST*)BIG;
    UST* x3h  = OH;

    // ---- weight prep (every call; ws is re-poisoned) ----
    auto nb = [](long n) { return (unsigned)((n + 255) / 256); };
    prep_t_kernel<<<dim3(48, 32), 256, 0, stream>>>(qkv_w, qkvWh, qkvWl, 3072, 1024);
    prep_t_kernel<<<dim3(16, 32), 256, 0, stream>>>(ao_w, aoWh, aoWl, 1024, 1024);
    for (int k = 0; k < 3; k++)
        prep_w_kernel<<<nb(1024L * 1024), 256, 0, stream>>>(conv_w + k, convCh, convCl,
                                                            1024, 3, 3072, 3072, k * 1024, 1024L * 1024);
    for (int e = 0; e < 8; e++)
        prep_t_kernel<<<dim3(16, 32), 256, 0, stream>>>(exp_w + (long)e * 1048576, expW + (long)e * 1048576,
                                                        nullptr, 1024, 1024);
    prep_t_kernel<<<dim3(64, 32), 256, 0, stream>>>(ff_w1, ff1W, nullptr, 4096, 1024);
    prep_t_kernel<<<dim3(16, 128), 256, 0, stream>>>(ff_w2, ff2W, nullptr, 1024, 4096);

    ln_pad_kernel<<<8, 256, 0, stream>>>(LNh, LNl);
    hipMemsetAsync(entacc, 0, 4, stream);
    hipMemsetAsync(cnt8, 0, 32, stream);

    // ---- attention block ----
    ln_split_kernel<<<8192, 256, 0, stream>>>(x, ln1_g, ln1_b, LNh, LNl);
    gemm_bt_kernel<2, true, 0, false><<<dim3(24, 64), 256, 0, stream>>>(
        LNh, LNl, qkvWh, qkvWl, qkv_b, nullptr, nullptr, nullptr, Sp,
        8192, 3072, 1024, 1024, 2, 4, nullptr, nullptr, nullptr);
    attn_mfma_kernel<<<512, 256, 0, stream>>>(Sp, OH, OL);
    gemm_bt_kernel<0, true, 0, false><<<dim3(8, 64), 256, 0, stream>>>(
        OH, OL, aoWh, aoWl, ao_b, x, out, nullptr, nullptr,
        8192, 1024, 1024, 1024, 0, 0, nullptr, nullptr, nullptr);
    // ---- dilated conv block: ONE fused GEMM, K=3072 (3 shifted segments) ----
    ln_split_kernel<<<8192, 256, 0, stream>>>(out, ln2_g, ln2_b, LNh, LNl);
    gemm_bt_kernel<0, true, 1024, false><<<dim3(8, 64), 256, 0, stream>>>(
        LNh, LNl, convCh, convCl, conv_b, out, out, nullptr, nullptr,
        8192, 1024, 3072, 1024, 0, 4, nullptr, nullptr, nullptr);
    // ---- MoE: gate -> sparse gathered expert GEMM (top-2 only, exact) ----
    ln_split_kernel<<<8192, 256, 0, stream>>>(out, ln3_g, ln3_b, LNh, LNl);
    gate_kernel<<<2048, 256, 0, stream>>>(LNh, LNl, gate_w, gate_b, combine, entacc, cnt8, perm);
    ent_final_kernel<<<1, 1, 0, stream>>>(entacc, out + 8388608);
    gemm_bt_kernel<3, false, 0, true><<<dim3(8, 136), 256, 0, stream>>>(
        LNh, nullptr, expW, nullptr, exp_b, nullptr, out, nullptr, nullptr,
        8192, 1024, 1024, 1024, 0, 0, cnt8, perm, combine);
    // ---- FFN ----
    f32_to_bf16_kernel<<<8192, 256, 0, stream>>>(out, x3h);
    gemm_bt_kernel<1, false, 0, false><<<dim3(32, 64), 256, 0, stream>>>(
        x3h, nullptr, ff1W, nullptr, ff_b1, nullptr, nullptr, h1, nullptr,
        8192, 4096, 1024, 1024, 0, 0, nullptr, nullptr, nullptr);
    gemm_bt_kernel<0, false, 0, false><<<dim3(8, 64), 256, 0, stream>>>(
        h1, nullptr, ff2W, nullptr, ff_b2, out, out, nullptr, nullptr,
        8192, 1024, 4096, 4096, 0, 0, nullptr, nullptr, nullptr);
}